// Round 3
// baseline (885.067 us; speedup 1.0000x reference)
//
#include <hip/hip_runtime.h>
#include <math.h>

// ---------------------------------------------------------------------------
// Problem constants
// ---------------------------------------------------------------------------
#define NN 50000          // nodes
#define NE 800000         // edges (before self loops)
#define NEP (NE + NN)     // edges incl self loops
#define NGR 64            // graphs
#define NHEAD 8
#define MPAD 50048        // 391 * 128
#define KSTASH 6          // register-stashed logits cover deg<=48; exact fallback beyond

typedef short short8 __attribute__((ext_vector_type(8)));
typedef float floatx4 __attribute__((ext_vector_type(4)));
typedef unsigned uintx4 __attribute__((ext_vector_type(4)));

__device__ inline float bf2f(short s) {
    union { unsigned u; float f; } v;
    v.u = ((unsigned)(unsigned short)s) << 16;
    return v.f;
}
__device__ inline float bf2f_lo(unsigned p) {
    union { unsigned u; float f; } v; v.u = p << 16; return v.f;
}
__device__ inline float bf2f_hi(unsigned p) {
    union { unsigned u; float f; } v; v.u = p & 0xffff0000u; return v.f;
}
__device__ inline short f2bf(float f) {
    union { float f; unsigned u; } v; v.f = f;
    unsigned r = v.u + 0x7fffu + ((v.u >> 16) & 1u);   // RNE
    return (short)(r >> 16);
}

// async global->LDS, 16 B per lane; lds dst = wave-uniform base + lane*16
__device__ inline void gl_lds16(const short* g, short* l) {
    __builtin_amdgcn_global_load_lds(
        (const __attribute__((address_space(1))) unsigned int*)g,
        (__attribute__((address_space(3))) unsigned int*)l, 16, 0, 0);
}

// ---------------------------------------------------------------------------
// CSR build (dst-major). Edge e<NE: src=ei[e], dst=ei[NE+e]; else self loop.
// ---------------------------------------------------------------------------
__global__ void count_deg(const int* __restrict__ ei, int* __restrict__ deg) {
    int e = blockIdx.x * 256 + threadIdx.x;
    if (e >= NEP) return;
    int d = (e < NE) ? ei[NE + e] : (e - NE);
    atomicAdd(&deg[d], 1);
}

__global__ __launch_bounds__(1024) void scan_local(const int* __restrict__ deg,
                                                   int* __restrict__ out,
                                                   int* __restrict__ bsum, int n) {
    __shared__ int sd[1024];
    int b = blockIdx.x, t = threadIdx.x;
    int i = b * 1024 + t;
    int v = (i < n) ? deg[i] : 0;
    sd[t] = v;
    __syncthreads();
    for (int off = 1; off < 1024; off <<= 1) {
        int tmp = (t >= off) ? sd[t - off] : 0;
        __syncthreads();
        sd[t] += tmp;
        __syncthreads();
    }
    if (i < n) out[i] = sd[t] - v;          // exclusive
    if (t == 1023) bsum[b] = sd[1023];
}

__global__ void scan_bsum(int* __restrict__ bsum, int nb) {
    if (threadIdx.x == 0) {
        int s = 0;
        for (int i = 0; i < nb; i++) { int v = bsum[i]; bsum[i] = s; s += v; }
        bsum[nb] = s;
    }
}

__global__ void scan_add(int* __restrict__ row_ptr, int* __restrict__ cursor,
                         const int* __restrict__ bsum, int n, int nb) {
    int i = blockIdx.x * 256 + threadIdx.x;
    if (i < n) {
        int v = row_ptr[i] + bsum[i >> 10];
        row_ptr[i] = v;
        cursor[i] = v;
    } else if (i == n) {
        row_ptr[n] = bsum[nb];
    }
}

__global__ void scatter_edges(const int* __restrict__ ei, int* __restrict__ cursor,
                              int* __restrict__ srcs) {
    int e = blockIdx.x * 256 + threadIdx.x;
    if (e >= NEP) return;
    int s, d;
    if (e < NE) { s = ei[e]; d = ei[NE + e]; }
    else        { s = e - NE; d = e - NE; }
    int pos = atomicAdd(&cursor[d], 1);
    srcs[pos] = s;
}

// ---------------------------------------------------------------------------
// fp32 -> bf16 conversions
// ---------------------------------------------------------------------------
__global__ void conv_w_all(const float* __restrict__ w0, const float* __restrict__ w1,
                           const float* __restrict__ w2, const float* __restrict__ w3,
                           short* __restrict__ out) {
    int i = blockIdx.x * 256 + threadIdx.x;          // 0 .. 294911
    if (i >= 294912) return;
    const float* src; int off;
    if (i < 65536)       { src = w0; off = i; }
    else if (i < 196608) { src = w1; off = i - 65536; }
    else if (i < 229376) { src = w2; off = i - 196608; }
    else                 { src = w3; off = i - 229376; }
    out[i] = f2bf(src[off]);
}

__global__ void conv_x_pad4(const float* __restrict__ x, short* __restrict__ xb) {
    int i = blockIdx.x * 256 + threadIdx.x;          // one float4 per thread
    if (i >= MPAD * 32) return;
    int r = i >> 5;
    short4 o;
    if (r < NN) {
        float4 v = *(const float4*)&x[(size_t)i * 4];
        o.x = f2bf(v.x); o.y = f2bf(v.y); o.z = f2bf(v.z); o.w = f2bf(v.w);
    } else {
        o.x = o.y = o.z = o.w = 0;
    }
    *(short4*)&xb[(size_t)i * 4] = o;
}

// ---------------------------------------------------------------------------
// bf16 MFMA GEMM + fused es/ed epilogue, async global_load_lds staging.
// XOR-swizzled unpadded LDS, BK=64, 128x128 tile, 4 waves. (unchanged R8 cfg)
// ---------------------------------------------------------------------------
template <int C>
__global__ __launch_bounds__(256) void gemm_bf(const short* __restrict__ A,
                                               const short* __restrict__ B,
                                               short* __restrict__ Cout,
                                               const float* __restrict__ a_s,
                                               const float* __restrict__ a_d,
                                               float* __restrict__ es,
                                               float* __restrict__ ed,
                                               int K) {
    constexpr int Nc = 8 * C;
    constexpr int colTiles = Nc / 128;
    constexpr int JPH = C / 16;        // j-frags per head within a wave
    constexpr int HPW = 64 / C;        // heads fully covered by one wave
    __shared__ __align__(16) short As[128 * 64];
    __shared__ __align__(16) short Bs[128 * 64];
    int bx = blockIdx.x % colTiles;
    int by = blockIdx.x / colTiles;
    int row0 = by * 128, col0 = bx * 128;
    int t = threadIdx.x;
    int lane = t & 63, w = t >> 6;
    int wr = (w >> 1) * 64, wc = (w & 1) * 64;
    int lrow = lane & 15, lq = lane >> 4;

    int srow = lane >> 3;              // 0..7 row within 8-row group
    int kcsrc = (lane & 7) ^ srow;     // swizzled source k-chunk

    floatx4 acc[4][4];
#pragma unroll
    for (int i = 0; i < 4; i++)
#pragma unroll
        for (int j = 0; j < 4; j++) acc[i][j] = (floatx4)0.0f;

    for (int k0 = 0; k0 < K; k0 += 64) {
#pragma unroll
        for (int it = 0; it < 4; it++) {
            int r0 = w * 32 + it * 8;
            int r = r0 + srow;
            gl_lds16(&A[(size_t)(row0 + r) * K + k0 + kcsrc * 8], &As[r0 * 64]);
            gl_lds16(&B[(size_t)(col0 + r) * K + k0 + kcsrc * 8], &Bs[r0 * 64]);
        }
        __syncthreads();
#pragma unroll
        for (int kk = 0; kk < 2; kk++) {
            int slot = (kk * 4 + lq) ^ (lrow & 7);
            short8 af[4], bfr[4];
#pragma unroll
            for (int i = 0; i < 4; i++)
                af[i] = *(const short8*)&As[(wr + i * 16 + lrow) * 64 + slot * 8];
#pragma unroll
            for (int j = 0; j < 4; j++)
                bfr[j] = *(const short8*)&Bs[(wc + j * 16 + lrow) * 64 + slot * 8];
#pragma unroll
            for (int i = 0; i < 4; i++)
#pragma unroll
                for (int j = 0; j < 4; j++)
                    acc[i][j] = __builtin_amdgcn_mfma_f32_16x16x32_bf16(af[i], bfr[j], acc[i][j], 0, 0, 0);
        }
        __syncthreads();
    }

    // ---- C store (D layout: row=wr+i*16+lq*4+r, col=wc+j*16+lrow)
#pragma unroll
    for (int i = 0; i < 4; i++)
#pragma unroll
        for (int j = 0; j < 4; j++)
#pragma unroll
            for (int r = 0; r < 4; r++) {
                int row = row0 + wr + i * 16 + lq * 4 + r;
                int col = col0 + wc + j * 16 + lrow;
                Cout[(size_t)row * Nc + col] = f2bf(acc[i][j][r]);
            }

    // ---- fused es/ed epilogue (a_s flat [H*C] == abs col index)
    float asv[4], adv[4];
#pragma unroll
    for (int j = 0; j < 4; j++) {
        int colA = col0 + wc + j * 16 + lrow;
        asv[j] = a_s[colA];
        adv[j] = a_d[colA];
    }
    int hb = (col0 + wc) / C;
#pragma unroll
    for (int i = 0; i < 4; i++)
#pragma unroll
        for (int r = 0; r < 4; r++) {
            float s_h[HPW], d_h[HPW];
#pragma unroll
            for (int hh = 0; hh < HPW; hh++) { s_h[hh] = 0.f; d_h[hh] = 0.f; }
#pragma unroll
            for (int j = 0; j < 4; j++) {
                s_h[j / JPH] = fmaf(acc[i][j][r], asv[j], s_h[j / JPH]);
                d_h[j / JPH] = fmaf(acc[i][j][r], adv[j], d_h[j / JPH]);
            }
#pragma unroll
            for (int hh = 0; hh < HPW; hh++) {
#pragma unroll
                for (int off = 1; off <= 8; off <<= 1) {
                    s_h[hh] += __shfl_xor(s_h[hh], off);
                    d_h[hh] += __shfl_xor(d_h[hh], off);
                }
            }
            if (lrow == 0) {
                int row = row0 + wr + i * 16 + lq * 4 + r;
                if (row < NN) {
#pragma unroll
                    for (int hh = 0; hh < HPW; hh++) {
                        es[row * 8 + hb + hh] = s_h[hh];
                        ed[row * 8 + hb + hh] = d_h[hh];
                    }
                }
            }
        }
}

// ---------------------------------------------------------------------------
// R13 split-attention (R12 resubmit; theory corrected to phase-locality).
// Kernel 1 (alpha): one wave per node, online softmax over incoming edges,
// logits register-stashed (deg<=48; exact recompute fallback beyond).
// Writes normalized alpha HEAD-MAJOR: alpha[h*NEP + e] — each aggr chunk
// streams a dense 4B/edge slice exactly once (edge-major [e][8] would cost
// NCH x 32B/edge of line-granularity over-fetch: ~600 MB over 4 layers).
// ---------------------------------------------------------------------------
__global__ __launch_bounds__(256) void alpha_kernel(const float* __restrict__ es,
                                                    const float* __restrict__ ed,
                                                    const int* __restrict__ row_ptr,
                                                    const int* __restrict__ srcs,
                                                    float* __restrict__ alpha) {
    int wave = threadIdx.x >> 6, lane = threadIdx.x & 63;
    int n = blockIdx.x * 4 + wave;     // grid = NN/4 exactly
    int start = row_ptr[n];
    int deg = row_ptr[n + 1] - start;
    int m8 = deg * 8;
    int hh = lane & 7;                 // idx&7 == lane&7 for idx = lane+i*64
    float edv = ed[n * 8 + hh];
    float st[KSTASH];
    float pm = -1e30f, ps = 0.f;
#pragma unroll
    for (int i = 0; i < KSTASH; i++) {
        int idx = lane + i * 64;
        if (idx < m8) {
            int s = srcs[start + (idx >> 3)];
            float e = es[s * 8 + hh] + edv;
            e = e > 0.f ? e : 0.2f * e;
            st[i] = e;
            float mn = fmaxf(pm, e);
            ps = ps * __expf(pm - mn) + __expf(e - mn);
            pm = mn;
        }
    }
    for (int idx = lane + KSTASH * 64; idx < m8; idx += 64) {   // rare
        int s = srcs[start + (idx >> 3)];
        float e = es[s * 8 + hh] + edv;
        e = e > 0.f ? e : 0.2f * e;
        float mn = fmaxf(pm, e);
        ps = ps * __expf(pm - mn) + __expf(e - mn);
        pm = mn;
    }
    // per-head reduce: head lives on lane&7; combine lane bits 3,4,5
#pragma unroll
    for (int off = 8; off <= 32; off <<= 1) {
        float mo = __shfl_xor(pm, off);
        float so = __shfl_xor(ps, off);
        float mn = fmaxf(pm, mo);
        ps = ps * __expf(pm - mn) + so * __expf(mo - mn);
        pm = mn;
    }
    float invd = 1.0f / ps;
    // head-major write: lane (k-group, head hh) -> alpha[hh*NEP + start + k]
#pragma unroll
    for (int i = 0; i < KSTASH; i++) {
        int idx = lane + i * 64;
        if (idx < m8)
            alpha[(size_t)hh * NEP + start + (idx >> 3)] = __expf(st[i] - pm) * invd;
    }
    for (int idx = lane + KSTASH * 64; idx < m8; idx += 64) {   // rare
        int s = srcs[start + (idx >> 3)];
        float e = es[s * 8 + hh] + edv;
        e = e > 0.f ? e : 0.2f * e;
        alpha[(size_t)hh * NEP + start + (idx >> 3)] = __expf(e - pm) * invd;
    }
}

// ---------------------------------------------------------------------------
// Kernel 2 (aggregate): feature-chunked gather.
// Mechanism (corrected R13 theory): chunking the feature dim into 64-channel
// slabs (one 128B line per h row) cuts the per-L2 gather working set from
// 51MB to 6.4MB (50000 x 128B) -> ~60% capacity-hit in the 4MiB per-XCD L2,
// vs the unchunked design's ~0% (R7-R10: 3.8 TB/s L3 random-access plateau).
// chunk = blockIdx % NCH keeps every slab continuously resident on a fixed
// XCD subset (deduplicated, no phase transitions); the mapping itself is
// secondary to the working-set cut. Zero LDS, low VGPR.
// Per edge: 8 lanes x 16B = 128B row-chunk; 8 edge groups per wave, U=2 ILP.
// alpha read is a dense head-major 4B/edge stream per chunk.
// ---------------------------------------------------------------------------
template <int C, bool ELU>
__global__ __launch_bounds__(256) void aggr_chunk(const short* __restrict__ h,
                                                  const float* __restrict__ alpha,
                                                  const int* __restrict__ row_ptr,
                                                  const int* __restrict__ srcs,
                                                  const float* __restrict__ bias,
                                                  short* __restrict__ out) {
    constexpr int HC = NHEAD * C;
    constexpr int NCH = HC / 64;       // 8 / 4 / 2 chunks
    constexpr int NPW = 4;             // nodes per wave
    int chunk = blockIdx.x % NCH;
    int grp   = blockIdx.x / NCH;
    int wave = threadIdx.x >> 6, lane = threadIdx.x & 63;
    int sub = lane & 7;                // channel octet within chunk
    int g   = lane >> 3;               // edge group 0..7
    int c0 = chunk * 64 + sub * 8;     // absolute channel of this lane's 16B
    int head = c0 / C;
    const float* ah = alpha + (size_t)head * NEP;
    int nbase = (grp * 4 + wave) * NPW;
    for (int ni = 0; ni < NPW; ni++) {
        int n = nbase + ni;
        int start = row_ptr[n];
        int deg = row_ptr[n + 1] - start;
        float acc[8];
#pragma unroll
        for (int j = 0; j < 8; j++) acc[j] = 0.f;
        int k = g;
        for (; k + 8 < deg; k += 16) {             // U=2: 2 rows in flight
            int s0 = srcs[start + k];
            int s1 = srcs[start + k + 8];
            float w0 = ah[start + k];
            float w1 = ah[start + k + 8];
            uintx4 h0 = *(const uintx4*)&h[(size_t)s0 * HC + c0];
            uintx4 h1 = *(const uintx4*)&h[(size_t)s1 * HC + c0];
#pragma unroll
            for (int j = 0; j < 4; j++) {
                acc[2 * j]     = fmaf(w0, bf2f_lo(h0[j]), acc[2 * j]);
                acc[2 * j + 1] = fmaf(w0, bf2f_hi(h0[j]), acc[2 * j + 1]);
            }
#pragma unroll
            for (int j = 0; j < 4; j++) {
                acc[2 * j]     = fmaf(w1, bf2f_lo(h1[j]), acc[2 * j]);
                acc[2 * j + 1] = fmaf(w1, bf2f_hi(h1[j]), acc[2 * j + 1]);
            }
        }
        for (; k < deg; k += 8) {
            int s0 = srcs[start + k];
            float w0 = ah[start + k];
            uintx4 h0 = *(const uintx4*)&h[(size_t)s0 * HC + c0];
#pragma unroll
            for (int j = 0; j < 4; j++) {
                acc[2 * j]     = fmaf(w0, bf2f_lo(h0[j]), acc[2 * j]);
                acc[2 * j + 1] = fmaf(w0, bf2f_hi(h0[j]), acc[2 * j + 1]);
            }
        }
        // reduce the 8 edge groups (lane bits 3,4,5)
#pragma unroll
        for (int j = 0; j < 8; j++) {
            acc[j] += __shfl_xor(acc[j], 8);
            acc[j] += __shfl_xor(acc[j], 16);
            acc[j] += __shfl_xor(acc[j], 32);
        }
        if (lane < 8) {                // lane == sub
            int cc = chunk * 64 + lane * 8;
            floatx4 b0 = *(const floatx4*)&bias[cc];
            floatx4 b1 = *(const floatx4*)&bias[cc + 4];
            float bb[8] = {b0[0], b0[1], b0[2], b0[3], b1[0], b1[1], b1[2], b1[3]};
            unsigned pk[4];
#pragma unroll
            for (int j = 0; j < 4; j++) {
                float o0 = acc[2 * j] + bb[2 * j];
                float o1 = acc[2 * j + 1] + bb[2 * j + 1];
                if (ELU) {
                    o0 = o0 > 0.f ? o0 : (__expf(o0) - 1.0f);
                    o1 = o1 > 0.f ? o1 : (__expf(o1) - 1.0f);
                }
                pk[j] = ((unsigned)(unsigned short)f2bf(o0)) |
                        (((unsigned)(unsigned short)f2bf(o1)) << 16);
            }
            *(uintx4*)&out[(size_t)n * HC + cc] = *(uintx4*)pk;
        }
    }
}

// ---------------------------------------------------------------------------
// Global mean pool: 64 graphs x 8 chunks of 64 ch; 16B/lane loads,
// shfl stripe-reduce within wave, tiny LDS combine across 4 waves.
// ---------------------------------------------------------------------------
__global__ __launch_bounds__(256) void pool_kernel(const short* __restrict__ h,
                                                   const int* __restrict__ batch,
                                                   float* __restrict__ gout) {
    __shared__ float red[4 * 64];
    int g = blockIdx.x >> 3;
    int fc = (blockIdx.x & 7) * 64;
    int lo = 0, hi = NN;
    while (lo < hi) { int mid = (lo + hi) >> 1; if (batch[mid] < g) lo = mid + 1; else hi = mid; }
    int s = lo;
    lo = 0; hi = NN;
    while (lo < hi) { int mid = (lo + hi) >> 1; if (batch[mid] < g + 1) lo = mid + 1; else hi = mid; }
    int e = lo;
    int t = threadIdx.x;
    int wave = t >> 6, lane = t & 63;
    int f8 = (lane & 7) * 8;           // 8 channels per lane within the 64-chunk
    int stripe = wave * 8 + (lane >> 3);   // 0..31 row stripes
    float acc[8];
#pragma unroll
    for (int j = 0; j < 8; j++) acc[j] = 0.f;
    for (int r = s + stripe; r < e; r += 32) {
        short8 v = *(const short8*)&h[(size_t)r * 512 + fc + f8];
#pragma unroll
        for (int j = 0; j < 8; j++) acc[j] += bf2f(v[j]);
    }
    // reduce 8 stripes within the wave (lane bits 3,4,5)
#pragma unroll
    for (int j = 0; j < 8; j++) {
        acc[j] += __shfl_xor(acc[j], 8);
        acc[j] += __shfl_xor(acc[j], 16);
        acc[j] += __shfl_xor(acc[j], 32);
    }
    if (lane < 8) {
#pragma unroll
        for (int j = 0; j < 8; j++) red[wave * 64 + lane * 8 + j] = acc[j];
    }
    __syncthreads();
    if (t < 64) {                      // t = ch within chunk
        float v = red[t] + red[64 + t] + red[128 + t] + red[192 + t];
        float inv = 1.0f / fmaxf((float)(e - s), 1.0f);
        gout[g * 512 + fc + t] = v * inv;
    }
}

// ---------------------------------------------------------------------------
// Final MLP: [64,512] -> elu(@lw1^T+lb1) -> @lw2^T+lb2 -> [64,2]
// ---------------------------------------------------------------------------
__global__ __launch_bounds__(64) void mlp_kernel(const float* __restrict__ g,
                                                 const float* __restrict__ lw1,
                                                 const float* __restrict__ lb1,
                                                 const float* __restrict__ lw2,
                                                 const float* __restrict__ lb2,
                                                 float* __restrict__ outp) {
    __shared__ float gv[512];
    __shared__ float y1[32];
    int b = blockIdx.x, t = threadIdx.x;
    for (int i = t; i < 512; i += 64) gv[i] = g[b * 512 + i];
    __syncthreads();
    if (t < 32) {
        float a = lb1[t];
        for (int k = 0; k < 512; k++) a = fmaf(gv[k], lw1[t * 512 + k], a);
        y1[t] = a > 0.f ? a : (__expf(a) - 1.0f);
    }
    __syncthreads();
    if (t < 2) {
        float a = lb2[t];
        for (int k = 0; k < 32; k++) a = fmaf(y1[k], lw2[t * 32 + k], a);
        outp[b * 2 + t] = a;
    }
}

// ---------------------------------------------------------------------------
// Launch
// ---------------------------------------------------------------------------
extern "C" void kernel_launch(void* const* d_in, const int* in_sizes, int n_in,
                              void* d_out, int out_size, void* d_ws, size_t ws_size,
                              hipStream_t stream) {
    (void)in_sizes; (void)n_in; (void)out_size; (void)ws_size;
    const float* x     = (const float*)d_in[0];
    const int*   ei    = (const int*)d_in[1];
    const int*   batch = (const int*)d_in[2];
    const float* W[4]  = {(const float*)d_in[3], (const float*)d_in[7],
                          (const float*)d_in[11], (const float*)d_in[15]};
    const float* As_[4] = {(const float*)d_in[4], (const float*)d_in[8],
                           (const float*)d_in[12], (const float*)d_in[16]};
    const float* Ad_[4] = {(const float*)d_in[5], (const float*)d_in[9],
                           (const float*)d_in[13], (const float*)d_in[17]};
    const float* Bi[4]  = {(const float*)d_in[6], (const float*)d_in[10],
                           (const float*)d_in[14], (const float*)d_in[18]};
    const float* lw1 = (const float*)d_in[19];
    const float* lb1 = (const float*)d_in[20];
    const float* lw2 = (const float*)d_in[21];
    const float* lb2 = (const float*)d_in[22];
    float* out = (float*)d_out;

    // workspace layout (bf16 buffers as short)
    short* Ab = (short*)d_ws;                      // [MPAD*512] activations
    short* Hb = Ab + (size_t)MPAD * 512;           // [MPAD*512] h = act @ W^T
    short* Wb = Hb + (size_t)MPAD * 512;           // bf16 weights (contiguous)
    short* Wb_[4] = {Wb, Wb + 65536, Wb + 196608, Wb + 229376};
    float* esb  = (float*)(Wb + 294912);           // [NN*8]
    float* edb  = esb + NN * NHEAD;                // [NN*8]
    float* gbuf = edb + NN * NHEAD;                // [64*512]
    int* row_ptr = (int*)(gbuf + NGR * 512);       // [NN+1]
    int* cursor  = row_ptr + (NN + 1);             // [NN+1]
    int* srcs    = cursor + (NN + 1);              // [NEP]
    int* bsum    = srcs + NEP;                     // [64]
    float* alphab = (float*)(bsum + 64);           // [8*NEP] head-major alpha

    const int nblk = (NN + 1023) / 1024;           // 49

    // ---- CSR build (shared by all 4 layers)
    hipMemsetAsync(cursor, 0, NN * sizeof(int), stream);
    count_deg<<<(NEP + 255) / 256, 256, 0, stream>>>(ei, cursor);
    scan_local<<<nblk, 1024, 0, stream>>>(cursor, row_ptr, bsum, NN);
    scan_bsum<<<1, 64, 0, stream>>>(bsum, nblk);
    scan_add<<<(NN + 256) / 256, 256, 0, stream>>>(row_ptr, cursor, bsum, NN, nblk);
    scatter_edges<<<(NEP + 255) / 256, 256, 0, stream>>>(ei, cursor, srcs);

    // ---- bf16 conversions
    conv_x_pad4<<<(MPAD * 32 + 255) / 256, 256, 0, stream>>>(x, Ab);
    conv_w_all<<<(294912 + 255) / 256, 256, 0, stream>>>(W[0], W[1], W[2], W[3], Wb);

    const int rowTiles = MPAD / 128;               // 391
    const int ag  = NN / 4;                        // alpha grid: 1 wave/node
    const int ngp = NN / 16;                       // aggr node groups (16 nodes/blk)

    // ---- layer 1: 128 -> 512 (C=64), ELU
    gemm_bf<64><<<rowTiles * 4, 256, 0, stream>>>(Ab, Wb_[0], Hb, As_[0], Ad_[0], esb, edb, 128);
    alpha_kernel<<<ag, 256, 0, stream>>>(esb, edb, row_ptr, srcs, alphab);
    aggr_chunk<64, true><<<ngp * 8, 256, 0, stream>>>(Hb, alphab, row_ptr, srcs, Bi[0], Ab);

    // ---- layer 2: 512 -> 256 (C=32), ELU
    gemm_bf<32><<<rowTiles * 2, 256, 0, stream>>>(Ab, Wb_[1], Hb, As_[1], Ad_[1], esb, edb, 512);
    alpha_kernel<<<ag, 256, 0, stream>>>(esb, edb, row_ptr, srcs, alphab);
    aggr_chunk<32, true><<<ngp * 4, 256, 0, stream>>>(Hb, alphab, row_ptr, srcs, Bi[1], Ab);

    // ---- layer 3: 256 -> 128 (C=16), ELU
    gemm_bf<16><<<rowTiles * 1, 256, 0, stream>>>(Ab, Wb_[2], Hb, As_[2], Ad_[2], esb, edb, 256);
    alpha_kernel<<<ag, 256, 0, stream>>>(esb, edb, row_ptr, srcs, alphab);
    aggr_chunk<16, true><<<ngp * 2, 256, 0, stream>>>(Hb, alphab, row_ptr, srcs, Bi[2], Ab);

    // ---- layer 4: 128 -> 512 (C=64), no ELU
    gemm_bf<64><<<rowTiles * 4, 256, 0, stream>>>(Ab, Wb_[3], Hb, As_[3], Ad_[3], esb, edb, 128);
    alpha_kernel<<<ag, 256, 0, stream>>>(esb, edb, row_ptr, srcs, alphab);
    aggr_chunk<64, false><<<ngp * 8, 256, 0, stream>>>(Hb, alphab, row_ptr, srcs, Bi[3], Ab);

    // ---- pool + MLP
    pool_kernel<<<NGR * 8, 256, 0, stream>>>(Ab, batch, gbuf);
    mlp_kernel<<<NGR, 64, 0, stream>>>(gbuf, lw1, lb1, lw2, lb2, out);
}

// Round 9
// 844.623 us; speedup vs baseline: 1.0479x; 1.0479x over previous
//
#include <hip/hip_runtime.h>
#include <math.h>

// ---------------------------------------------------------------------------
// Problem constants
// ---------------------------------------------------------------------------
#define NN 50000          // nodes
#define NE 800000         // edges (before self loops)
#define NEP (NE + NN)     // edges incl self loops
#define NGR 64            // graphs
#define NHEAD 8
#define MPAD 50048        // 391 * 128
#define KSTASH 6          // register-stashed logits cover deg<=48; exact fallback beyond

typedef short short8 __attribute__((ext_vector_type(8)));
typedef float floatx4 __attribute__((ext_vector_type(4)));
typedef unsigned uintx4 __attribute__((ext_vector_type(4)));

__device__ inline float bf2f(short s) {
    union { unsigned u; float f; } v;
    v.u = ((unsigned)(unsigned short)s) << 16;
    return v.f;
}
__device__ inline float bf2f_lo(unsigned p) {
    union { unsigned u; float f; } v; v.u = p << 16; return v.f;
}
__device__ inline float bf2f_hi(unsigned p) {
    union { unsigned u; float f; } v; v.u = p & 0xffff0000u; return v.f;
}
__device__ inline short f2bf(float f) {
    union { float f; unsigned u; } v; v.f = f;
    unsigned r = v.u + 0x7fffu + ((v.u >> 16) & 1u);   // RNE
    return (short)(r >> 16);
}

// async global->LDS, 16 B per lane; lds dst = wave-uniform base + lane*16
__device__ inline void gl_lds16(const short* g, short* l) {
    __builtin_amdgcn_global_load_lds(
        (const __attribute__((address_space(1))) unsigned int*)g,
        (__attribute__((address_space(3))) unsigned int*)l, 16, 0, 0);
}

// ---------------------------------------------------------------------------
// CSR build (dst-major). Edge e<NE: src=ei[e], dst=ei[NE+e]; else self loop.
// ---------------------------------------------------------------------------
__global__ void count_deg(const int* __restrict__ ei, int* __restrict__ deg) {
    int e = blockIdx.x * 256 + threadIdx.x;
    if (e >= NEP) return;
    int d = (e < NE) ? ei[NE + e] : (e - NE);
    atomicAdd(&deg[d], 1);
}

__global__ __launch_bounds__(1024) void scan_local(const int* __restrict__ deg,
                                                   int* __restrict__ out,
                                                   int* __restrict__ bsum, int n) {
    __shared__ int sd[1024];
    int b = blockIdx.x, t = threadIdx.x;
    int i = b * 1024 + t;
    int v = (i < n) ? deg[i] : 0;
    sd[t] = v;
    __syncthreads();
    for (int off = 1; off < 1024; off <<= 1) {
        int tmp = (t >= off) ? sd[t - off] : 0;
        __syncthreads();
        sd[t] += tmp;
        __syncthreads();
    }
    if (i < n) out[i] = sd[t] - v;          // exclusive
    if (t == 1023) bsum[b] = sd[1023];
}

__global__ void scan_bsum(int* __restrict__ bsum, int nb) {
    if (threadIdx.x == 0) {
        int s = 0;
        for (int i = 0; i < nb; i++) { int v = bsum[i]; bsum[i] = s; s += v; }
        bsum[nb] = s;
    }
}

__global__ void scan_add(int* __restrict__ row_ptr, int* __restrict__ cursor,
                         const int* __restrict__ bsum, int n, int nb) {
    int i = blockIdx.x * 256 + threadIdx.x;
    if (i < n) {
        int v = row_ptr[i] + bsum[i >> 10];
        row_ptr[i] = v;
        cursor[i] = v;
    } else if (i == n) {
        row_ptr[n] = bsum[nb];
    }
}

__global__ void scatter_edges(const int* __restrict__ ei, int* __restrict__ cursor,
                              int* __restrict__ srcs) {
    int e = blockIdx.x * 256 + threadIdx.x;
    if (e >= NEP) return;
    int s, d;
    if (e < NE) { s = ei[e]; d = ei[NE + e]; }
    else        { s = e - NE; d = e - NE; }
    int pos = atomicAdd(&cursor[d], 1);
    srcs[pos] = s;
}

// ---------------------------------------------------------------------------
// fp32 -> bf16 conversions
// ---------------------------------------------------------------------------
__global__ void conv_w_all(const float* __restrict__ w0, const float* __restrict__ w1,
                           const float* __restrict__ w2, const float* __restrict__ w3,
                           short* __restrict__ out) {
    int i = blockIdx.x * 256 + threadIdx.x;          // 0 .. 294911
    if (i >= 294912) return;
    const float* src; int off;
    if (i < 65536)       { src = w0; off = i; }
    else if (i < 196608) { src = w1; off = i - 65536; }
    else if (i < 229376) { src = w2; off = i - 196608; }
    else                 { src = w3; off = i - 229376; }
    out[i] = f2bf(src[off]);
}

__global__ void conv_x_pad4(const float* __restrict__ x, short* __restrict__ xb) {
    int i = blockIdx.x * 256 + threadIdx.x;          // one float4 per thread
    if (i >= MPAD * 32) return;
    int r = i >> 5;
    short4 o;
    if (r < NN) {
        float4 v = *(const float4*)&x[(size_t)i * 4];
        o.x = f2bf(v.x); o.y = f2bf(v.y); o.z = f2bf(v.z); o.w = f2bf(v.w);
    } else {
        o.x = o.y = o.z = o.w = 0;
    }
    *(short4*)&xb[(size_t)i * 4] = o;
}

// ---------------------------------------------------------------------------
// bf16 MFMA GEMM + fused es/ed epilogue, async global_load_lds staging.
// XOR-swizzled unpadded LDS, BK=64, 128x128 tile, 4 waves. (unchanged R8 cfg)
// ---------------------------------------------------------------------------
template <int C>
__global__ __launch_bounds__(256) void gemm_bf(const short* __restrict__ A,
                                               const short* __restrict__ B,
                                               short* __restrict__ Cout,
                                               const float* __restrict__ a_s,
                                               const float* __restrict__ a_d,
                                               float* __restrict__ es,
                                               float* __restrict__ ed,
                                               int K) {
    constexpr int Nc = 8 * C;
    constexpr int colTiles = Nc / 128;
    constexpr int JPH = C / 16;        // j-frags per head within a wave
    constexpr int HPW = 64 / C;        // heads fully covered by one wave
    __shared__ __align__(16) short As[128 * 64];
    __shared__ __align__(16) short Bs[128 * 64];
    int bx = blockIdx.x % colTiles;
    int by = blockIdx.x / colTiles;
    int row0 = by * 128, col0 = bx * 128;
    int t = threadIdx.x;
    int lane = t & 63, w = t >> 6;
    int wr = (w >> 1) * 64, wc = (w & 1) * 64;
    int lrow = lane & 15, lq = lane >> 4;

    int srow = lane >> 3;              // 0..7 row within 8-row group
    int kcsrc = (lane & 7) ^ srow;     // swizzled source k-chunk

    floatx4 acc[4][4];
#pragma unroll
    for (int i = 0; i < 4; i++)
#pragma unroll
        for (int j = 0; j < 4; j++) acc[i][j] = (floatx4)0.0f;

    for (int k0 = 0; k0 < K; k0 += 64) {
#pragma unroll
        for (int it = 0; it < 4; it++) {
            int r0 = w * 32 + it * 8;
            int r = r0 + srow;
            gl_lds16(&A[(size_t)(row0 + r) * K + k0 + kcsrc * 8], &As[r0 * 64]);
            gl_lds16(&B[(size_t)(col0 + r) * K + k0 + kcsrc * 8], &Bs[r0 * 64]);
        }
        __syncthreads();
#pragma unroll
        for (int kk = 0; kk < 2; kk++) {
            int slot = (kk * 4 + lq) ^ (lrow & 7);
            short8 af[4], bfr[4];
#pragma unroll
            for (int i = 0; i < 4; i++)
                af[i] = *(const short8*)&As[(wr + i * 16 + lrow) * 64 + slot * 8];
#pragma unroll
            for (int j = 0; j < 4; j++)
                bfr[j] = *(const short8*)&Bs[(wc + j * 16 + lrow) * 64 + slot * 8];
#pragma unroll
            for (int i = 0; i < 4; i++)
#pragma unroll
                for (int j = 0; j < 4; j++)
                    acc[i][j] = __builtin_amdgcn_mfma_f32_16x16x32_bf16(af[i], bfr[j], acc[i][j], 0, 0, 0);
        }
        __syncthreads();
    }

    // ---- C store (D layout: row=wr+i*16+lq*4+r, col=wc+j*16+lrow)
#pragma unroll
    for (int i = 0; i < 4; i++)
#pragma unroll
        for (int j = 0; j < 4; j++)
#pragma unroll
            for (int r = 0; r < 4; r++) {
                int row = row0 + wr + i * 16 + lq * 4 + r;
                int col = col0 + wc + j * 16 + lrow;
                Cout[(size_t)row * Nc + col] = f2bf(acc[i][j][r]);
            }

    // ---- fused es/ed epilogue (a_s flat [H*C] == abs col index)
    float asv[4], adv[4];
#pragma unroll
    for (int j = 0; j < 4; j++) {
        int colA = col0 + wc + j * 16 + lrow;
        asv[j] = a_s[colA];
        adv[j] = a_d[colA];
    }
    int hb = (col0 + wc) / C;
#pragma unroll
    for (int i = 0; i < 4; i++)
#pragma unroll
        for (int r = 0; r < 4; r++) {
            float s_h[HPW], d_h[HPW];
#pragma unroll
            for (int hh = 0; hh < HPW; hh++) { s_h[hh] = 0.f; d_h[hh] = 0.f; }
#pragma unroll
            for (int j = 0; j < 4; j++) {
                s_h[j / JPH] = fmaf(acc[i][j][r], asv[j], s_h[j / JPH]);
                d_h[j / JPH] = fmaf(acc[i][j][r], adv[j], d_h[j / JPH]);
            }
#pragma unroll
            for (int hh = 0; hh < HPW; hh++) {
#pragma unroll
                for (int off = 1; off <= 8; off <<= 1) {
                    s_h[hh] += __shfl_xor(s_h[hh], off);
                    d_h[hh] += __shfl_xor(d_h[hh], off);
                }
            }
            if (lrow == 0) {
                int row = row0 + wr + i * 16 + lq * 4 + r;
                if (row < NN) {
#pragma unroll
                    for (int hh = 0; hh < HPW; hh++) {
                        es[row * 8 + hb + hh] = s_h[hh];
                        ed[row * 8 + hb + hh] = d_h[hh];
                    }
                }
            }
        }
}

// ---------------------------------------------------------------------------
// R14 split-attention. alpha: one wave per node, online softmax, register-
// stashed logits, HEAD-MAJOR alpha[h*NEP+e]. R14: scalarized n/start/deg
// (readfirstlane -> s_load + scalar loop control).
// ---------------------------------------------------------------------------
__global__ __launch_bounds__(256) void alpha_kernel(const float* __restrict__ es,
                                                    const float* __restrict__ ed,
                                                    const int* __restrict__ row_ptr,
                                                    const int* __restrict__ srcs,
                                                    float* __restrict__ alpha) {
    int wave = threadIdx.x >> 6, lane = threadIdx.x & 63;
    int n = __builtin_amdgcn_readfirstlane(blockIdx.x * 4 + wave);
    int start = row_ptr[n];            // uniform -> s_load
    int deg = row_ptr[n + 1] - start;
    int m8 = deg * 8;
    const int* sp = srcs + start;      // uniform base
    float* ap = alpha + start;         // uniform base
    int hh = lane & 7;                 // idx&7 == lane&7 for idx = lane+i*64
    int hoff = hh * NEP;               // per-lane head-major offset
    float edv = ed[n * 8 + hh];
    float st[KSTASH];
    float pm = -1e30f, ps = 0.f;
#pragma unroll
    for (int i = 0; i < KSTASH; i++) {
        int idx = lane + i * 64;
        if (idx < m8) {
            int s = sp[idx >> 3];
            float e = es[s * 8 + hh] + edv;
            e = e > 0.f ? e : 0.2f * e;
            st[i] = e;
            float mn = fmaxf(pm, e);
            ps = ps * __expf(pm - mn) + __expf(e - mn);
            pm = mn;
        }
    }
    for (int idx = lane + KSTASH * 64; idx < m8; idx += 64) {   // rare
        int s = sp[idx >> 3];
        float e = es[s * 8 + hh] + edv;
        e = e > 0.f ? e : 0.2f * e;
        float mn = fmaxf(pm, e);
        ps = ps * __expf(pm - mn) + __expf(e - mn);
        pm = mn;
    }
    // per-head reduce: head lives on lane&7; combine lane bits 3,4,5
#pragma unroll
    for (int off = 8; off <= 32; off <<= 1) {
        float mo = __shfl_xor(pm, off);
        float so = __shfl_xor(ps, off);
        float mn = fmaxf(pm, mo);
        ps = ps * __expf(pm - mn) + so * __expf(mo - mn);
        pm = mn;
    }
    float invd = 1.0f / ps;
    // head-major write: lane (k-group, head hh) -> alpha[hh*NEP + start + k]
#pragma unroll
    for (int i = 0; i < KSTASH; i++) {
        int idx = lane + i * 64;
        if (idx < m8) ap[hoff + (idx >> 3)] = __expf(st[i] - pm) * invd;
    }
    for (int idx = lane + KSTASH * 64; idx < m8; idx += 64) {   // rare
        int s = sp[idx >> 3];
        float e = es[s * 8 + hh] + edv;
        e = e > 0.f ? e : 0.2f * e;
        ap[hoff + (idx >> 3)] = __expf(e - pm) * invd;
    }
}

// ---------------------------------------------------------------------------
// Kernel 2 (aggregate): feature-chunked gather. R13 counters: 72% L2 hit
// (FETCH 241MB vs 870MB requested), VALUBusy 80%, HBM 22% -> issue-bound.
// R14: cut per-edge instruction overhead with zero traffic change:
//  - readfirstlane(n) -> start/deg via s_load; scalar trip count nit=deg>>4
//    (verified identical edge coverage to old k+8<deg condition) -> scalar
//    loop control, no exec-mask churn.
//  - uniform bases (srcs+start, alpha+start, h) + 32-bit byte offsets ->
//    global_load_*_saddr; h address = 1 lshl + 1 add instead of 64-bit chain.
// Structure/traffic identical to R13: chunk = blockIdx % NCH, 8 lanes x 16B
// per edge, U=2 ILP, head-major alpha stream. (U=2 matched to mean deg 17:
// nit is 1 for typical nodes; U=4 would push all work to the remainder.)
// Post-R14 candidate (R8 analysis): node-per-group aggr — 1 node per 8-lane
// group, serial edge walk, no cross-group shfl reduce (48 VALU/node saved).
// ---------------------------------------------------------------------------
template <int C, bool ELU>
__global__ __launch_bounds__(256) void aggr_chunk(const short* __restrict__ h,
                                                  const float* __restrict__ alpha,
                                                  const int* __restrict__ row_ptr,
                                                  const int* __restrict__ srcs,
                                                  const float* __restrict__ bias,
                                                  short* __restrict__ out) {
    constexpr int HC = NHEAD * C;
    constexpr int NCH = HC / 64;       // 8 / 4 / 2 chunks
    constexpr int NPW = 4;             // nodes per wave
    constexpr int RSH = (C == 64) ? 10 : (C == 32) ? 9 : 8;   // log2(HC*2)
    int chunk = blockIdx.x % NCH;
    int grp   = blockIdx.x / NCH;
    int wave = threadIdx.x >> 6, lane = threadIdx.x & 63;
    int sub = lane & 7;                // channel octet within chunk
    int g   = lane >> 3;               // edge group 0..7
    int c0 = chunk * 64 + sub * 8;     // absolute channel of this lane's 16B
    unsigned c02 = (unsigned)(c0 * 2); // byte offset within row
    int head = c0 / C;
    int hoff = head * NEP;             // per-lane head-major alpha offset
    int nbase = (grp * 4 + wave) * NPW;
    for (int ni = 0; ni < NPW; ni++) {
        int n = __builtin_amdgcn_readfirstlane(nbase + ni);
        int start = row_ptr[n];        // uniform -> s_load
        int deg = row_ptr[n + 1] - start;
        const int* sp = srcs + start;  // uniform base -> saddr form
        const float* ap = alpha + start;
        int nit = deg >> 4;            // scalar trip count (U=2, 16 edges/iter)
        float acc[8];
#pragma unroll
        for (int j = 0; j < 8; j++) acc[j] = 0.f;
        int kb = g;
        for (int it = 0; it < nit; ++it, kb += 16) {
            int s0 = sp[kb];
            int s1 = sp[kb + 8];
            float w0 = ap[hoff + kb];
            float w1 = ap[hoff + kb + 8];
            uintx4 h0 = *(const uintx4*)((const char*)h + (((unsigned)s0 << RSH) + c02));
            uintx4 h1 = *(const uintx4*)((const char*)h + (((unsigned)s1 << RSH) + c02));
#pragma unroll
            for (int j = 0; j < 4; j++) {
                acc[2 * j]     = fmaf(w0, bf2f_lo(h0[j]), acc[2 * j]);
                acc[2 * j + 1] = fmaf(w0, bf2f_hi(h0[j]), acc[2 * j + 1]);
            }
#pragma unroll
            for (int j = 0; j < 4; j++) {
                acc[2 * j]     = fmaf(w1, bf2f_lo(h1[j]), acc[2 * j]);
                acc[2 * j + 1] = fmaf(w1, bf2f_hi(h1[j]), acc[2 * j + 1]);
            }
        }
        for (int k = kb; k < deg; k += 8) {   // remainder (<=2 per group)
            int s0 = sp[k];
            float w0 = ap[hoff + k];
            uintx4 h0 = *(const uintx4*)((const char*)h + (((unsigned)s0 << RSH) + c02));
#pragma unroll
            for (int j = 0; j < 4; j++) {
                acc[2 * j]     = fmaf(w0, bf2f_lo(h0[j]), acc[2 * j]);
                acc[2 * j + 1] = fmaf(w0, bf2f_hi(h0[j]), acc[2 * j + 1]);
            }
        }
        // reduce the 8 edge groups (lane bits 3,4,5)
#pragma unroll
        for (int j = 0; j < 8; j++) {
            acc[j] += __shfl_xor(acc[j], 8);
            acc[j] += __shfl_xor(acc[j], 16);
            acc[j] += __shfl_xor(acc[j], 32);
        }
        if (lane < 8) {                // lane == sub
            int cc = chunk * 64 + lane * 8;
            floatx4 b0 = *(const floatx4*)&bias[cc];
            floatx4 b1 = *(const floatx4*)&bias[cc + 4];
            float bb[8] = {b0[0], b0[1], b0[2], b0[3], b1[0], b1[1], b1[2], b1[3]};
            unsigned pk[4];
#pragma unroll
            for (int j = 0; j < 4; j++) {
                float o0 = acc[2 * j] + bb[2 * j];
                float o1 = acc[2 * j + 1] + bb[2 * j + 1];
                if (ELU) {
                    o0 = o0 > 0.f ? o0 : (__expf(o0) - 1.0f);
                    o1 = o1 > 0.f ? o1 : (__expf(o1) - 1.0f);
                }
                pk[j] = ((unsigned)(unsigned short)f2bf(o0)) |
                        (((unsigned)(unsigned short)f2bf(o1)) << 16);
            }
            *(uintx4*)&out[(size_t)n * HC + cc] = *(uintx4*)pk;
        }
    }
}

// ---------------------------------------------------------------------------
// Global mean pool: 64 graphs x 8 chunks of 64 ch; 16B/lane loads,
// shfl stripe-reduce within wave, tiny LDS combine across 4 waves.
// ---------------------------------------------------------------------------
__global__ __launch_bounds__(256) void pool_kernel(const short* __restrict__ h,
                                                   const int* __restrict__ batch,
                                                   float* __restrict__ gout) {
    __shared__ float red[4 * 64];
    int g = blockIdx.x >> 3;
    int fc = (blockIdx.x & 7) * 64;
    int lo = 0, hi = NN;
    while (lo < hi) { int mid = (lo + hi) >> 1; if (batch[mid] < g) lo = mid + 1; else hi = mid; }
    int s = lo;
    lo = 0; hi = NN;
    while (lo < hi) { int mid = (lo + hi) >> 1; if (batch[mid] < g + 1) lo = mid + 1; else hi = mid; }
    int e = lo;
    int t = threadIdx.x;
    int wave = t >> 6, lane = t & 63;
    int f8 = (lane & 7) * 8;           // 8 channels per lane within the 64-chunk
    int stripe = wave * 8 + (lane >> 3);   // 0..31 row stripes
    float acc[8];
#pragma unroll
    for (int j = 0; j < 8; j++) acc[j] = 0.f;
    for (int r = s + stripe; r < e; r += 32) {
        short8 v = *(const short8*)&h[(size_t)r * 512 + fc + f8];
#pragma unroll
        for (int j = 0; j < 8; j++) acc[j] += bf2f(v[j]);
    }
    // reduce 8 stripes within the wave (lane bits 3,4,5)
#pragma unroll
    for (int j = 0; j < 8; j++) {
        acc[j] += __shfl_xor(acc[j], 8);
        acc[j] += __shfl_xor(acc[j], 16);
        acc[j] += __shfl_xor(acc[j], 32);
    }
    if (lane < 8) {
#pragma unroll
        for (int j = 0; j < 8; j++) red[wave * 64 + lane * 8 + j] = acc[j];
    }
    __syncthreads();
    if (t < 64) {                      // t = ch within chunk
        float v = red[t] + red[64 + t] + red[128 + t] + red[192 + t];
        float inv = 1.0f / fmaxf((float)(e - s), 1.0f);
        gout[g * 512 + fc + t] = v * inv;
    }
}

// ---------------------------------------------------------------------------
// Final MLP: [64,512] -> elu(@lw1^T+lb1) -> @lw2^T+lb2 -> [64,2]
// ---------------------------------------------------------------------------
__global__ __launch_bounds__(64) void mlp_kernel(const float* __restrict__ g,
                                                 const float* __restrict__ lw1,
                                                 const float* __restrict__ lb1,
                                                 const float* __restrict__ lw2,
                                                 const float* __restrict__ lb2,
                                                 float* __restrict__ outp) {
    __shared__ float gv[512];
    __shared__ float y1[32];
    int b = blockIdx.x, t = threadIdx.x;
    for (int i = t; i < 512; i += 64) gv[i] = g[b * 512 + i];
    __syncthreads();
    if (t < 32) {
        float a = lb1[t];
        for (int k = 0; k < 512; k++) a = fmaf(gv[k], lw1[t * 512 + k], a);
        y1[t] = a > 0.f ? a : (__expf(a) - 1.0f);
    }
    __syncthreads();
    if (t < 2) {
        float a = lb2[t];
        for (int k = 0; k < 32; k++) a = fmaf(y1[k], lw2[t * 32 + k], a);
        outp[b * 2 + t] = a;
    }
}

// ---------------------------------------------------------------------------
// Launch
// ---------------------------------------------------------------------------
extern "C" void kernel_launch(void* const* d_in, const int* in_sizes, int n_in,
                              void* d_out, int out_size, void* d_ws, size_t ws_size,
                              hipStream_t stream) {
    (void)in_sizes; (void)n_in; (void)out_size; (void)ws_size;
    const float* x     = (const float*)d_in[0];
    const int*   ei    = (const int*)d_in[1];
    const int*   batch = (const int*)d_in[2];
    const float* W[4]  = {(const float*)d_in[3], (const float*)d_in[7],
                          (const float*)d_in[11], (const float*)d_in[15]};
    const float* As_[4] = {(const float*)d_in[4], (const float*)d_in[8],
                           (const float*)d_in[12], (const float*)d_in[16]};
    const float* Ad_[4] = {(const float*)d_in[5], (const float*)d_in[9],
                           (const float*)d_in[13], (const float*)d_in[17]};
    const float* Bi[4]  = {(const float*)d_in[6], (const float*)d_in[10],
                           (const float*)d_in[14], (const float*)d_in[18]};
    const float* lw1 = (const float*)d_in[19];
    const float* lb1 = (const float*)d_in[20];
    const float* lw2 = (const float*)d_in[21];
    const float* lb2 = (const float*)d_in[22];
    float* out = (float*)d_out;

    // workspace layout (bf16 buffers as short)
    short* Ab = (short*)d_ws;                      // [MPAD*512] activations
    short* Hb = Ab + (size_t)MPAD * 512;           // [MPAD*512] h = act @ W^T
    short* Wb = Hb + (size_t)MPAD * 512;           // bf16 weights (contiguous)
    short* Wb_[4] = {Wb, Wb + 65536, Wb + 196608, Wb + 229376};
    float* esb  = (float*)(Wb + 294912);           // [NN*8]
    float* edb  = esb + NN * NHEAD;                // [NN*8]
    float* gbuf = edb + NN * NHEAD;                // [64*512]
    int* row_ptr = (int*)(gbuf + NGR * 512);       // [NN+1]
    int* cursor  = row_ptr + (NN + 1);             // [NN+1]
    int* srcs    = cursor + (NN + 1);              // [NEP]
    int* bsum    = srcs + NEP;                     // [64]
    float* alphab = (float*)(bsum + 64);           // [8*NEP] head-major alpha

    const int nblk = (NN + 1023) / 1024;           // 49

    // ---- CSR build (shared by all 4 layers)
    hipMemsetAsync(cursor, 0, NN * sizeof(int), stream);
    count_deg<<<(NEP + 255) / 256, 256, 0, stream>>>(ei, cursor);
    scan_local<<<nblk, 1024, 0, stream>>>(cursor, row_ptr, bsum, NN);
    scan_bsum<<<1, 64, 0, stream>>>(bsum, nblk);
    scan_add<<<(NN + 256) / 256, 256, 0, stream>>>(row_ptr, cursor, bsum, NN, nblk);
    scatter_edges<<<(NEP + 255) / 256, 256, 0, stream>>>(ei, cursor, srcs);

    // ---- bf16 conversions
    conv_x_pad4<<<(MPAD * 32 + 255) / 256, 256, 0, stream>>>(x, Ab);
    conv_w_all<<<(294912 + 255) / 256, 256, 0, stream>>>(W[0], W[1], W[2], W[3], Wb);

    const int rowTiles = MPAD / 128;               // 391
    const int ag  = NN / 4;                        // alpha grid: 1 wave/node
    const int ngp = NN / 16;                       // aggr node groups (16 nodes/blk)

    // ---- layer 1: 128 -> 512 (C=64), ELU
    gemm_bf<64><<<rowTiles * 4, 256, 0, stream>>>(Ab, Wb_[0], Hb, As_[0], Ad_[0], esb, edb, 128);
    alpha_kernel<<<ag, 256, 0, stream>>>(esb, edb, row_ptr, srcs, alphab);
    aggr_chunk<64, true><<<ngp * 8, 256, 0, stream>>>(Hb, alphab, row_ptr, srcs, Bi[0], Ab);

    // ---- layer 2: 512 -> 256 (C=32), ELU
    gemm_bf<32><<<rowTiles * 2, 256, 0, stream>>>(Ab, Wb_[1], Hb, As_[1], Ad_[1], esb, edb, 512);
    alpha_kernel<<<ag, 256, 0, stream>>>(esb, edb, row_ptr, srcs, alphab);
    aggr_chunk<32, true><<<ngp * 4, 256, 0, stream>>>(Hb, alphab, row_ptr, srcs, Bi[1], Ab);

    // ---- layer 3: 256 -> 128 (C=16), ELU
    gemm_bf<16><<<rowTiles * 1, 256, 0, stream>>>(Ab, Wb_[2], Hb, As_[2], Ad_[2], esb, edb, 256);
    alpha_kernel<<<ag, 256, 0, stream>>>(esb, edb, row_ptr, srcs, alphab);
    aggr_chunk<16, true><<<ngp * 2, 256, 0, stream>>>(Hb, alphab, row_ptr, srcs, Bi[2], Ab);

    // ---- layer 4: 128 -> 512 (C=64), no ELU
    gemm_bf<64><<<rowTiles * 4, 256, 0, stream>>>(Ab, Wb_[3], Hb, As_[3], Ad_[3], esb, edb, 128);
    alpha_kernel<<<ag, 256, 0, stream>>>(esb, edb, row_ptr, srcs, alphab);
    aggr_chunk<64, false><<<ngp * 8, 256, 0, stream>>>(Hb, alphab, row_ptr, srcs, Bi[3], Ab);

    // ---- pool + MLP
    pool_kernel<<<NGR * 8, 256, 0, stream>>>(Ab, batch, gbuf);
    mlp_kernel<<<NGR, 64, 0, stream>>>(gbuf, lw1, lb1, lw2, lb2, out);
}

// Round 10
// 776.163 us; speedup vs baseline: 1.1403x; 1.0882x over previous
//
#include <hip/hip_runtime.h>
#include <math.h>

// ---------------------------------------------------------------------------
// Problem constants
// ---------------------------------------------------------------------------
#define NN 50000          // nodes
#define NE 800000         // edges (before self loops)
#define NEP (NE + NN)     // edges incl self loops
#define NGR 64            // graphs
#define NHEAD 8
#define MPAD 50048        // 391 * 128
#define KSTASH 6          // register-stashed logits cover deg<=48; exact fallback beyond

typedef short short8 __attribute__((ext_vector_type(8)));
typedef float floatx4 __attribute__((ext_vector_type(4)));
typedef unsigned uintx4 __attribute__((ext_vector_type(4)));

__device__ inline float bf2f(short s) {
    union { unsigned u; float f; } v;
    v.u = ((unsigned)(unsigned short)s) << 16;
    return v.f;
}
__device__ inline float bf2f_lo(unsigned p) {
    union { unsigned u; float f; } v; v.u = p << 16; return v.f;
}
__device__ inline float bf2f_hi(unsigned p) {
    union { unsigned u; float f; } v; v.u = p & 0xffff0000u; return v.f;
}
__device__ inline short f2bf(float f) {
    union { float f; unsigned u; } v; v.f = f;
    unsigned r = v.u + 0x7fffu + ((v.u >> 16) & 1u);   // RNE
    return (short)(r >> 16);
}

// async global->LDS, 16 B per lane; lds dst = wave-uniform base + lane*16
__device__ inline void gl_lds16(const short* g, short* l) {
    __builtin_amdgcn_global_load_lds(
        (const __attribute__((address_space(1))) unsigned int*)g,
        (__attribute__((address_space(3))) unsigned int*)l, 16, 0, 0);
}

// ---------------------------------------------------------------------------
// CSR build (dst-major). Edge e<NE: src=ei[e], dst=ei[NE+e]; else self loop.
// ---------------------------------------------------------------------------
__global__ void count_deg(const int* __restrict__ ei, int* __restrict__ deg) {
    int e = blockIdx.x * 256 + threadIdx.x;
    if (e >= NEP) return;
    int d = (e < NE) ? ei[NE + e] : (e - NE);
    atomicAdd(&deg[d], 1);
}

__global__ __launch_bounds__(1024) void scan_local(const int* __restrict__ deg,
                                                   int* __restrict__ out,
                                                   int* __restrict__ bsum, int n) {
    __shared__ int sd[1024];
    int b = blockIdx.x, t = threadIdx.x;
    int i = b * 1024 + t;
    int v = (i < n) ? deg[i] : 0;
    sd[t] = v;
    __syncthreads();
    for (int off = 1; off < 1024; off <<= 1) {
        int tmp = (t >= off) ? sd[t - off] : 0;
        __syncthreads();
        sd[t] += tmp;
        __syncthreads();
    }
    if (i < n) out[i] = sd[t] - v;          // exclusive
    if (t == 1023) bsum[b] = sd[1023];
}

__global__ void scan_bsum(int* __restrict__ bsum, int nb) {
    if (threadIdx.x == 0) {
        int s = 0;
        for (int i = 0; i < nb; i++) { int v = bsum[i]; bsum[i] = s; s += v; }
        bsum[nb] = s;
    }
}

__global__ void scan_add(int* __restrict__ row_ptr, int* __restrict__ cursor,
                         const int* __restrict__ bsum, int n, int nb) {
    int i = blockIdx.x * 256 + threadIdx.x;
    if (i < n) {
        int v = row_ptr[i] + bsum[i >> 10];
        row_ptr[i] = v;
        cursor[i] = v;
    } else if (i == n) {
        row_ptr[n] = bsum[nb];
    }
}

__global__ void scatter_edges(const int* __restrict__ ei, int* __restrict__ cursor,
                              int* __restrict__ srcs) {
    int e = blockIdx.x * 256 + threadIdx.x;
    if (e >= NEP) return;
    int s, d;
    if (e < NE) { s = ei[e]; d = ei[NE + e]; }
    else        { s = e - NE; d = e - NE; }
    int pos = atomicAdd(&cursor[d], 1);
    srcs[pos] = s;
}

// ---------------------------------------------------------------------------
// fp32 -> bf16 conversions
// ---------------------------------------------------------------------------
__global__ void conv_w_all(const float* __restrict__ w0, const float* __restrict__ w1,
                           const float* __restrict__ w2, const float* __restrict__ w3,
                           short* __restrict__ out) {
    int i = blockIdx.x * 256 + threadIdx.x;          // 0 .. 294911
    if (i >= 294912) return;
    const float* src; int off;
    if (i < 65536)       { src = w0; off = i; }
    else if (i < 196608) { src = w1; off = i - 65536; }
    else if (i < 229376) { src = w2; off = i - 196608; }
    else                 { src = w3; off = i - 229376; }
    out[i] = f2bf(src[off]);
}

__global__ void conv_x_pad4(const float* __restrict__ x, short* __restrict__ xb) {
    int i = blockIdx.x * 256 + threadIdx.x;          // one float4 per thread
    if (i >= MPAD * 32) return;
    int r = i >> 5;
    short4 o;
    if (r < NN) {
        float4 v = *(const float4*)&x[(size_t)i * 4];
        o.x = f2bf(v.x); o.y = f2bf(v.y); o.z = f2bf(v.z); o.w = f2bf(v.w);
    } else {
        o.x = o.y = o.z = o.w = 0;
    }
    *(short4*)&xb[(size_t)i * 4] = o;
}

// ---------------------------------------------------------------------------
// bf16 MFMA GEMM + fused es/ed epilogue, async global_load_lds staging.
// XOR-swizzled unpadded LDS, BK=64, 128x128 tile, 4 waves. (unchanged R8 cfg)
// ---------------------------------------------------------------------------
template <int C>
__global__ __launch_bounds__(256) void gemm_bf(const short* __restrict__ A,
                                               const short* __restrict__ B,
                                               short* __restrict__ Cout,
                                               const float* __restrict__ a_s,
                                               const float* __restrict__ a_d,
                                               float* __restrict__ es,
                                               float* __restrict__ ed,
                                               int K) {
    constexpr int Nc = 8 * C;
    constexpr int colTiles = Nc / 128;
    constexpr int JPH = C / 16;        // j-frags per head within a wave
    constexpr int HPW = 64 / C;        // heads fully covered by one wave
    __shared__ __align__(16) short As[128 * 64];
    __shared__ __align__(16) short Bs[128 * 64];
    int bx = blockIdx.x % colTiles;
    int by = blockIdx.x / colTiles;
    int row0 = by * 128, col0 = bx * 128;
    int t = threadIdx.x;
    int lane = t & 63, w = t >> 6;
    int wr = (w >> 1) * 64, wc = (w & 1) * 64;
    int lrow = lane & 15, lq = lane >> 4;

    int srow = lane >> 3;              // 0..7 row within 8-row group
    int kcsrc = (lane & 7) ^ srow;     // swizzled source k-chunk

    floatx4 acc[4][4];
#pragma unroll
    for (int i = 0; i < 4; i++)
#pragma unroll
        for (int j = 0; j < 4; j++) acc[i][j] = (floatx4)0.0f;

    for (int k0 = 0; k0 < K; k0 += 64) {
#pragma unroll
        for (int it = 0; it < 4; it++) {
            int r0 = w * 32 + it * 8;
            int r = r0 + srow;
            gl_lds16(&A[(size_t)(row0 + r) * K + k0 + kcsrc * 8], &As[r0 * 64]);
            gl_lds16(&B[(size_t)(col0 + r) * K + k0 + kcsrc * 8], &Bs[r0 * 64]);
        }
        __syncthreads();
#pragma unroll
        for (int kk = 0; kk < 2; kk++) {
            int slot = (kk * 4 + lq) ^ (lrow & 7);
            short8 af[4], bfr[4];
#pragma unroll
            for (int i = 0; i < 4; i++)
                af[i] = *(const short8*)&As[(wr + i * 16 + lrow) * 64 + slot * 8];
#pragma unroll
            for (int j = 0; j < 4; j++)
                bfr[j] = *(const short8*)&Bs[(wc + j * 16 + lrow) * 64 + slot * 8];
#pragma unroll
            for (int i = 0; i < 4; i++)
#pragma unroll
                for (int j = 0; j < 4; j++)
                    acc[i][j] = __builtin_amdgcn_mfma_f32_16x16x32_bf16(af[i], bfr[j], acc[i][j], 0, 0, 0);
        }
        __syncthreads();
    }

    // ---- C store (D layout: row=wr+i*16+lq*4+r, col=wc+j*16+lrow)
#pragma unroll
    for (int i = 0; i < 4; i++)
#pragma unroll
        for (int j = 0; j < 4; j++)
#pragma unroll
            for (int r = 0; r < 4; r++) {
                int row = row0 + wr + i * 16 + lq * 4 + r;
                int col = col0 + wc + j * 16 + lrow;
                Cout[(size_t)row * Nc + col] = f2bf(acc[i][j][r]);
            }

    // ---- fused es/ed epilogue (a_s flat [H*C] == abs col index)
    float asv[4], adv[4];
#pragma unroll
    for (int j = 0; j < 4; j++) {
        int colA = col0 + wc + j * 16 + lrow;
        asv[j] = a_s[colA];
        adv[j] = a_d[colA];
    }
    int hb = (col0 + wc) / C;
#pragma unroll
    for (int i = 0; i < 4; i++)
#pragma unroll
        for (int r = 0; r < 4; r++) {
            float s_h[HPW], d_h[HPW];
#pragma unroll
            for (int hh = 0; hh < HPW; hh++) { s_h[hh] = 0.f; d_h[hh] = 0.f; }
#pragma unroll
            for (int j = 0; j < 4; j++) {
                s_h[j / JPH] = fmaf(acc[i][j][r], asv[j], s_h[j / JPH]);
                d_h[j / JPH] = fmaf(acc[i][j][r], adv[j], d_h[j / JPH]);
            }
#pragma unroll
            for (int hh = 0; hh < HPW; hh++) {
#pragma unroll
                for (int off = 1; off <= 8; off <<= 1) {
                    s_h[hh] += __shfl_xor(s_h[hh], off);
                    d_h[hh] += __shfl_xor(d_h[hh], off);
                }
            }
            if (lrow == 0) {
                int row = row0 + wr + i * 16 + lq * 4 + r;
                if (row < NN) {
#pragma unroll
                    for (int hh = 0; hh < HPW; hh++) {
                        es[row * 8 + hb + hh] = s_h[hh];
                        ed[row * 8 + hb + hh] = d_h[hh];
                    }
                }
            }
        }
}

// ---------------------------------------------------------------------------
// alpha: one wave per node, online softmax, register-stashed logits,
// HEAD-MAJOR alpha[h*NEP+e]. Scalarized n/start/deg (R14, kept).
// ---------------------------------------------------------------------------
__global__ __launch_bounds__(256) void alpha_kernel(const float* __restrict__ es,
                                                    const float* __restrict__ ed,
                                                    const int* __restrict__ row_ptr,
                                                    const int* __restrict__ srcs,
                                                    float* __restrict__ alpha) {
    int wave = threadIdx.x >> 6, lane = threadIdx.x & 63;
    int n = __builtin_amdgcn_readfirstlane(blockIdx.x * 4 + wave);
    int start = row_ptr[n];            // uniform -> s_load
    int deg = row_ptr[n + 1] - start;
    int m8 = deg * 8;
    const int* sp = srcs + start;      // uniform base
    float* ap = alpha + start;         // uniform base
    int hh = lane & 7;                 // idx&7 == lane&7 for idx = lane+i*64
    int hoff = hh * NEP;               // per-lane head-major offset
    float edv = ed[n * 8 + hh];
    float st[KSTASH];
    float pm = -1e30f, ps = 0.f;
#pragma unroll
    for (int i = 0; i < KSTASH; i++) {
        int idx = lane + i * 64;
        if (idx < m8) {
            int s = sp[idx >> 3];
            float e = es[s * 8 + hh] + edv;
            e = e > 0.f ? e : 0.2f * e;
            st[i] = e;
            float mn = fmaxf(pm, e);
            ps = ps * __expf(pm - mn) + __expf(e - mn);
            pm = mn;
        }
    }
    for (int idx = lane + KSTASH * 64; idx < m8; idx += 64) {   // rare
        int s = sp[idx >> 3];
        float e = es[s * 8 + hh] + edv;
        e = e > 0.f ? e : 0.2f * e;
        float mn = fmaxf(pm, e);
        ps = ps * __expf(pm - mn) + __expf(e - mn);
        pm = mn;
    }
    // per-head reduce: head lives on lane&7; combine lane bits 3,4,5
#pragma unroll
    for (int off = 8; off <= 32; off <<= 1) {
        float mo = __shfl_xor(pm, off);
        float so = __shfl_xor(ps, off);
        float mn = fmaxf(pm, mo);
        ps = ps * __expf(pm - mn) + so * __expf(mo - mn);
        pm = mn;
    }
    float invd = 1.0f / ps;
    // head-major write: lane (k-group, head hh) -> alpha[hh*NEP + start + k]
#pragma unroll
    for (int i = 0; i < KSTASH; i++) {
        int idx = lane + i * 64;
        if (idx < m8) ap[hoff + (idx >> 3)] = __expf(st[i] - pm) * invd;
    }
    for (int idx = lane + KSTASH * 64; idx < m8; idx += 64) {   // rare
        int s = sp[idx >> 3];
        float e = es[s * 8 + hh] + edv;
        e = e > 0.f ? e : 0.2f * e;
        ap[hoff + (idx >> 3)] = __expf(e - pm) * invd;
    }
}

// ---------------------------------------------------------------------------
// R15 aggregate: NODE-PER-GROUP feature-chunked gather.
// R14 counters: 149us @ C=64, VALUBusy 78%, FETCH 242MB (72% L2 hit), still
// issue-bound. R7 arithmetic: at mean deg 17 the 8-group shfl reduce (48
// VALU/node) + per-node setup is ~half the instruction stream.
// R15: one node per 8-lane group (8 nodes/wave). Each lane owns the same 8
// channels across all edges of its node -> private accumulator, ZERO
// cross-lane reduce, all-64-lane stores. Per-edge cost identical (1 srcs +
// 1 alpha + 16B h + 16 VALU per lane). Cost: group-divergence -> wave runs
// max(deg of 8) ~ 24 iters vs mean 17. Net model ~110 -> ~70 instr/node.
// Traffic identical: same 128B row-chunks, chunk = blockIdx % NCH phase
// locality, head-major alpha (group-broadcast reads).
// ---------------------------------------------------------------------------
template <int C, bool ELU>
__global__ __launch_bounds__(256) void aggr_npg(const short* __restrict__ h,
                                                const float* __restrict__ alpha,
                                                const int* __restrict__ row_ptr,
                                                const int* __restrict__ srcs,
                                                const float* __restrict__ bias,
                                                short* __restrict__ out) {
    constexpr int HC = NHEAD * C;
    constexpr int NCH = HC / 64;       // 8 / 4 / 2 chunks
    constexpr int RSH = (C == 64) ? 10 : (C == 32) ? 9 : 8;   // log2(HC*2)
    int chunk = blockIdx.x % NCH;
    int grp   = blockIdx.x / NCH;      // 32-node block
    int lane = threadIdx.x & 63;
    int wave = threadIdx.x >> 6;
    int sub = lane & 7;                // channel octet within chunk
    int g   = lane >> 3;               // node group within wave 0..7
    int n = grp * 32 + wave * 8 + g;   // this group's node
    int c0 = chunk * 64 + sub * 8;     // absolute channel of this lane's 16B
    unsigned c02 = (unsigned)(c0 * 2); // byte offset within row
    int head = c0 / C;
    bool valid = n < NN;
    int start = 0, deg = 0;
    if (valid) {
        start = row_ptr[n];
        deg = row_ptr[n + 1] - start;
    }
    unsigned soff = (unsigned)start;                 // srcs elem offset
    unsigned aoff = (unsigned)(head * NEP + start);  // alpha elem offset
    float acc[8];
#pragma unroll
    for (int j = 0; j < 8; j++) acc[j] = 0.f;
    int k = 0;
    for (; k + 1 < deg; k += 2) {      // U=2: 2 edges of this node in flight
        int s0 = srcs[soff + k];
        int s1 = srcs[soff + k + 1];
        float w0 = alpha[aoff + k];
        float w1 = alpha[aoff + k + 1];
        uintx4 h0 = *(const uintx4*)((const char*)h + (((unsigned)s0 << RSH) + c02));
        uintx4 h1 = *(const uintx4*)((const char*)h + (((unsigned)s1 << RSH) + c02));
#pragma unroll
        for (int j = 0; j < 4; j++) {
            acc[2 * j]     = fmaf(w0, bf2f_lo(h0[j]), acc[2 * j]);
            acc[2 * j + 1] = fmaf(w0, bf2f_hi(h0[j]), acc[2 * j + 1]);
        }
#pragma unroll
        for (int j = 0; j < 4; j++) {
            acc[2 * j]     = fmaf(w1, bf2f_lo(h1[j]), acc[2 * j]);
            acc[2 * j + 1] = fmaf(w1, bf2f_hi(h1[j]), acc[2 * j + 1]);
        }
    }
    if (k < deg) {                     // odd-deg remainder (<=1)
        int s0 = srcs[soff + k];
        float w0 = alpha[aoff + k];
        uintx4 h0 = *(const uintx4*)((const char*)h + (((unsigned)s0 << RSH) + c02));
#pragma unroll
        for (int j = 0; j < 4; j++) {
            acc[2 * j]     = fmaf(w0, bf2f_lo(h0[j]), acc[2 * j]);
            acc[2 * j + 1] = fmaf(w0, bf2f_hi(h0[j]), acc[2 * j + 1]);
        }
    }
    if (valid) {
        floatx4 b0 = *(const floatx4*)&bias[c0];
        floatx4 b1 = *(const floatx4*)&bias[c0 + 4];
        float bb[8] = {b0[0], b0[1], b0[2], b0[3], b1[0], b1[1], b1[2], b1[3]};
        unsigned pk[4];
#pragma unroll
        for (int j = 0; j < 4; j++) {
            float o0 = acc[2 * j] + bb[2 * j];
            float o1 = acc[2 * j + 1] + bb[2 * j + 1];
            if (ELU) {
                o0 = o0 > 0.f ? o0 : (__expf(o0) - 1.0f);
                o1 = o1 > 0.f ? o1 : (__expf(o1) - 1.0f);
            }
            pk[j] = ((unsigned)(unsigned short)f2bf(o0)) |
                    (((unsigned)(unsigned short)f2bf(o1)) << 16);
        }
        *(uintx4*)&out[(size_t)n * HC + c0] = *(uintx4*)pk;
    }
}

// ---------------------------------------------------------------------------
// Global mean pool: 64 graphs x 8 chunks of 64 ch; 16B/lane loads,
// shfl stripe-reduce within wave, tiny LDS combine across 4 waves.
// ---------------------------------------------------------------------------
__global__ __launch_bounds__(256) void pool_kernel(const short* __restrict__ h,
                                                   const int* __restrict__ batch,
                                                   float* __restrict__ gout) {
    __shared__ float red[4 * 64];
    int g = blockIdx.x >> 3;
    int fc = (blockIdx.x & 7) * 64;
    int lo = 0, hi = NN;
    while (lo < hi) { int mid = (lo + hi) >> 1; if (batch[mid] < g) lo = mid + 1; else hi = mid; }
    int s = lo;
    lo = 0; hi = NN;
    while (lo < hi) { int mid = (lo + hi) >> 1; if (batch[mid] < g + 1) lo = mid + 1; else hi = mid; }
    int e = lo;
    int t = threadIdx.x;
    int wave = t >> 6, lane = t & 63;
    int f8 = (lane & 7) * 8;           // 8 channels per lane within the 64-chunk
    int stripe = wave * 8 + (lane >> 3);   // 0..31 row stripes
    float acc[8];
#pragma unroll
    for (int j = 0; j < 8; j++) acc[j] = 0.f;
    for (int r = s + stripe; r < e; r += 32) {
        short8 v = *(const short8*)&h[(size_t)r * 512 + fc + f8];
#pragma unroll
        for (int j = 0; j < 8; j++) acc[j] += bf2f(v[j]);
    }
    // reduce 8 stripes within the wave (lane bits 3,4,5)
#pragma unroll
    for (int j = 0; j < 8; j++) {
        acc[j] += __shfl_xor(acc[j], 8);
        acc[j] += __shfl_xor(acc[j], 16);
        acc[j] += __shfl_xor(acc[j], 32);
    }
    if (lane < 8) {
#pragma unroll
        for (int j = 0; j < 8; j++) red[wave * 64 + lane * 8 + j] = acc[j];
    }
    __syncthreads();
    if (t < 64) {                      // t = ch within chunk
        float v = red[t] + red[64 + t] + red[128 + t] + red[192 + t];
        float inv = 1.0f / fmaxf((float)(e - s), 1.0f);
        gout[g * 512 + fc + t] = v * inv;
    }
}

// ---------------------------------------------------------------------------
// Final MLP: [64,512] -> elu(@lw1^T+lb1) -> @lw2^T+lb2 -> [64,2]
// ---------------------------------------------------------------------------
__global__ __launch_bounds__(64) void mlp_kernel(const float* __restrict__ g,
                                                 const float* __restrict__ lw1,
                                                 const float* __restrict__ lb1,
                                                 const float* __restrict__ lw2,
                                                 const float* __restrict__ lb2,
                                                 float* __restrict__ outp) {
    __shared__ float gv[512];
    __shared__ float y1[32];
    int b = blockIdx.x, t = threadIdx.x;
    for (int i = t; i < 512; i += 64) gv[i] = g[b * 512 + i];
    __syncthreads();
    if (t < 32) {
        float a = lb1[t];
        for (int k = 0; k < 512; k++) a = fmaf(gv[k], lw1[t * 512 + k], a);
        y1[t] = a > 0.f ? a : (__expf(a) - 1.0f);
    }
    __syncthreads();
    if (t < 2) {
        float a = lb2[t];
        for (int k = 0; k < 32; k++) a = fmaf(y1[k], lw2[t * 32 + k], a);
        outp[b * 2 + t] = a;
    }
}

// ---------------------------------------------------------------------------
// Launch
// ---------------------------------------------------------------------------
extern "C" void kernel_launch(void* const* d_in, const int* in_sizes, int n_in,
                              void* d_out, int out_size, void* d_ws, size_t ws_size,
                              hipStream_t stream) {
    (void)in_sizes; (void)n_in; (void)out_size; (void)ws_size;
    const float* x     = (const float*)d_in[0];
    const int*   ei    = (const int*)d_in[1];
    const int*   batch = (const int*)d_in[2];
    const float* W[4]  = {(const float*)d_in[3], (const float*)d_in[7],
                          (const float*)d_in[11], (const float*)d_in[15]};
    const float* As_[4] = {(const float*)d_in[4], (const float*)d_in[8],
                           (const float*)d_in[12], (const float*)d_in[16]};
    const float* Ad_[4] = {(const float*)d_in[5], (const float*)d_in[9],
                           (const float*)d_in[13], (const float*)d_in[17]};
    const float* Bi[4]  = {(const float*)d_in[6], (const float*)d_in[10],
                           (const float*)d_in[14], (const float*)d_in[18]};
    const float* lw1 = (const float*)d_in[19];
    const float* lb1 = (const float*)d_in[20];
    const float* lw2 = (const float*)d_in[21];
    const float* lb2 = (const float*)d_in[22];
    float* out = (float*)d_out;

    // workspace layout (bf16 buffers as short)
    short* Ab = (short*)d_ws;                      // [MPAD*512] activations
    short* Hb = Ab + (size_t)MPAD * 512;           // [MPAD*512] h = act @ W^T
    short* Wb = Hb + (size_t)MPAD * 512;           // bf16 weights (contiguous)
    short* Wb_[4] = {Wb, Wb + 65536, Wb + 196608, Wb + 229376};
    float* esb  = (float*)(Wb + 294912);           // [NN*8]
    float* edb  = esb + NN * NHEAD;                // [NN*8]
    float* gbuf = edb + NN * NHEAD;                // [64*512]
    int* row_ptr = (int*)(gbuf + NGR * 512);       // [NN+1]
    int* cursor  = row_ptr + (NN + 1);             // [NN+1]
    int* srcs    = cursor + (NN + 1);              // [NEP]
    int* bsum    = srcs + NEP;                     // [64]
    float* alphab = (float*)(bsum + 64);           // [8*NEP] head-major alpha

    const int nblk = (NN + 1023) / 1024;           // 49

    // ---- CSR build (shared by all 4 layers)
    hipMemsetAsync(cursor, 0, NN * sizeof(int), stream);
    count_deg<<<(NEP + 255) / 256, 256, 0, stream>>>(ei, cursor);
    scan_local<<<nblk, 1024, 0, stream>>>(cursor, row_ptr, bsum, NN);
    scan_bsum<<<1, 64, 0, stream>>>(bsum, nblk);
    scan_add<<<(NN + 256) / 256, 256, 0, stream>>>(row_ptr, cursor, bsum, NN, nblk);
    scatter_edges<<<(NEP + 255) / 256, 256, 0, stream>>>(ei, cursor, srcs);

    // ---- bf16 conversions
    conv_x_pad4<<<(MPAD * 32 + 255) / 256, 256, 0, stream>>>(x, Ab);
    conv_w_all<<<(294912 + 255) / 256, 256, 0, stream>>>(W[0], W[1], W[2], W[3], Wb);

    const int rowTiles = MPAD / 128;               // 391
    const int ag  = NN / 4;                        // alpha grid: 1 wave/node
    const int ngb = (NN + 31) / 32;                // aggr: 32 nodes per block

    // ---- layer 1: 128 -> 512 (C=64), ELU
    gemm_bf<64><<<rowTiles * 4, 256, 0, stream>>>(Ab, Wb_[0], Hb, As_[0], Ad_[0], esb, edb, 128);
    alpha_kernel<<<ag, 256, 0, stream>>>(esb, edb, row_ptr, srcs, alphab);
    aggr_npg<64, true><<<ngb * 8, 256, 0, stream>>>(Hb, alphab, row_ptr, srcs, Bi[0], Ab);

    // ---- layer 2: 512 -> 256 (C=32), ELU
    gemm_bf<32><<<rowTiles * 2, 256, 0, stream>>>(Ab, Wb_[1], Hb, As_[1], Ad_[1], esb, edb, 512);
    alpha_kernel<<<ag, 256, 0, stream>>>(esb, edb, row_ptr, srcs, alphab);
    aggr_npg<32, true><<<ngb * 4, 256, 0, stream>>>(Hb, alphab, row_ptr, srcs, Bi[1], Ab);

    // ---- layer 3: 256 -> 128 (C=16), ELU
    gemm_bf<16><<<rowTiles * 1, 256, 0, stream>>>(Ab, Wb_[2], Hb, As_[2], Ad_[2], esb, edb, 256);
    alpha_kernel<<<ag, 256, 0, stream>>>(esb, edb, row_ptr, srcs, alphab);
    aggr_npg<16, true><<<ngb * 2, 256, 0, stream>>>(Hb, alphab, row_ptr, srcs, Bi[2], Ab);

    // ---- layer 4: 128 -> 512 (C=64), no ELU
    gemm_bf<64><<<rowTiles * 4, 256, 0, stream>>>(Ab, Wb_[3], Hb, As_[3], Ad_[3], esb, edb, 128);
    alpha_kernel<<<ag, 256, 0, stream>>>(esb, edb, row_ptr, srcs, alphab);
    aggr_npg<64, false><<<ngb * 8, 256, 0, stream>>>(Hb, alphab, row_ptr, srcs, Bi[3], Ab);

    // ---- pool + MLP
    pool_kernel<<<NGR * 8, 256, 0, stream>>>(Ab, batch, gbuf);
    mlp_kernel<<<NGR, 64, 0, stream>>>(gbuf, lw1, lb1, lw2, lb2, out);
}

// Round 11
// 761.523 us; speedup vs baseline: 1.1622x; 1.0192x over previous
//
#include <hip/hip_runtime.h>
#include <math.h>

// ---------------------------------------------------------------------------
// Problem constants
// ---------------------------------------------------------------------------
#define NN 50000          // nodes
#define NE 800000         // edges (before self loops)
#define NEP (NE + NN)     // real edges incl self loops
#define NEPP 1000000      // padded edge capacity: NEP + 3*NN
#define NGR 64            // graphs
#define NHEAD 8
#define MPAD 50048        // 391 * 128
#define KSTASH 6          // register-stashed logits cover deg<=48; exact fallback beyond

typedef short short8 __attribute__((ext_vector_type(8)));
typedef float floatx4 __attribute__((ext_vector_type(4)));
typedef unsigned uintx4 __attribute__((ext_vector_type(4)));

__device__ inline float bf2f(short s) {
    union { unsigned u; float f; } v;
    v.u = ((unsigned)(unsigned short)s) << 16;
    return v.f;
}
__device__ inline float bf2f_lo(unsigned p) {
    union { unsigned u; float f; } v; v.u = p << 16; return v.f;
}
__device__ inline float bf2f_hi(unsigned p) {
    union { unsigned u; float f; } v; v.u = p & 0xffff0000u; return v.f;
}
__device__ inline short f2bf(float f) {
    union { float f; unsigned u; } v; v.f = f;
    unsigned r = v.u + 0x7fffu + ((v.u >> 16) & 1u);   // RNE
    return (short)(r >> 16);
}

// async global->LDS, 16 B per lane; lds dst = wave-uniform base + lane*16
__device__ inline void gl_lds16(const short* g, short* l) {
    __builtin_amdgcn_global_load_lds(
        (const __attribute__((address_space(1))) unsigned int*)g,
        (__attribute__((address_space(3))) unsigned int*)l, 16, 0, 0);
}

// ---------------------------------------------------------------------------
// CSR build (dst-major), R16: degrees PADDED to %4==0 in row_ptr (uniform
// U=4 aggr loop, no tail); real degrees kept in degr[] for the softmax.
// Pad slots: srcs memset to 0 (gather row 0, L2-hot), alpha zero-filled.
// ---------------------------------------------------------------------------
__global__ void count_deg(const int* __restrict__ ei, int* __restrict__ deg) {
    int e = blockIdx.x * 256 + threadIdx.x;
    if (e >= NEP) return;
    int d = (e < NE) ? ei[NE + e] : (e - NE);
    atomicAdd(&deg[d], 1);
}

__global__ __launch_bounds__(1024) void scan_local(const int* __restrict__ deg,
                                                   int* __restrict__ out,
                                                   int* __restrict__ bsum, int n) {
    __shared__ int sd[1024];
    int b = blockIdx.x, t = threadIdx.x;
    int i = b * 1024 + t;
    int v = (i < n) ? ((deg[i] + 3) & ~3) : 0;   // padded degree
    sd[t] = v;
    __syncthreads();
    for (int off = 1; off < 1024; off <<= 1) {
        int tmp = (t >= off) ? sd[t - off] : 0;
        __syncthreads();
        sd[t] += tmp;
        __syncthreads();
    }
    if (i < n) out[i] = sd[t] - v;          // exclusive
    if (t == 1023) bsum[b] = sd[1023];
}

__global__ void scan_bsum(int* __restrict__ bsum, int nb) {
    if (threadIdx.x == 0) {
        int s = 0;
        for (int i = 0; i < nb; i++) { int v = bsum[i]; bsum[i] = s; s += v; }
        bsum[nb] = s;
    }
}

__global__ void scan_add(int* __restrict__ row_ptr, int* __restrict__ cursor,
                         const int* __restrict__ bsum, int n, int nb) {
    int i = blockIdx.x * 256 + threadIdx.x;
    if (i < n) {
        int v = row_ptr[i] + bsum[i >> 10];
        row_ptr[i] = v;
        cursor[i] = v;
    } else if (i == n) {
        row_ptr[n] = bsum[nb];
    }
}

__global__ void scatter_edges(const int* __restrict__ ei, int* __restrict__ cursor,
                              int* __restrict__ srcs) {
    int e = blockIdx.x * 256 + threadIdx.x;
    if (e >= NEP) return;
    int s, d;
    if (e < NE) { s = ei[e]; d = ei[NE + e]; }
    else        { s = e - NE; d = e - NE; }
    int pos = atomicAdd(&cursor[d], 1);
    srcs[pos] = s;
}

// ---------------------------------------------------------------------------
// fp32 -> bf16 conversions
// ---------------------------------------------------------------------------
__global__ void conv_w_all(const float* __restrict__ w0, const float* __restrict__ w1,
                           const float* __restrict__ w2, const float* __restrict__ w3,
                           short* __restrict__ out) {
    int i = blockIdx.x * 256 + threadIdx.x;          // 0 .. 294911
    if (i >= 294912) return;
    const float* src; int off;
    if (i < 65536)       { src = w0; off = i; }
    else if (i < 196608) { src = w1; off = i - 65536; }
    else if (i < 229376) { src = w2; off = i - 196608; }
    else                 { src = w3; off = i - 229376; }
    out[i] = f2bf(src[off]);
}

__global__ void conv_x_pad4(const float* __restrict__ x, short* __restrict__ xb) {
    int i = blockIdx.x * 256 + threadIdx.x;          // one float4 per thread
    if (i >= MPAD * 32) return;
    int r = i >> 5;
    short4 o;
    if (r < NN) {
        float4 v = *(const float4*)&x[(size_t)i * 4];
        o.x = f2bf(v.x); o.y = f2bf(v.y); o.z = f2bf(v.z); o.w = f2bf(v.w);
    } else {
        o.x = o.y = o.z = o.w = 0;
    }
    *(short4*)&xb[(size_t)i * 4] = o;
}

// ---------------------------------------------------------------------------
// bf16 MFMA GEMM + fused es/ed epilogue, async global_load_lds staging.
// XOR-swizzled unpadded LDS, BK=64, 128x128 tile, 4 waves. (unchanged R8 cfg)
// ---------------------------------------------------------------------------
template <int C>
__global__ __launch_bounds__(256) void gemm_bf(const short* __restrict__ A,
                                               const short* __restrict__ B,
                                               short* __restrict__ Cout,
                                               const float* __restrict__ a_s,
                                               const float* __restrict__ a_d,
                                               float* __restrict__ es,
                                               float* __restrict__ ed,
                                               int K) {
    constexpr int Nc = 8 * C;
    constexpr int colTiles = Nc / 128;
    constexpr int JPH = C / 16;        // j-frags per head within a wave
    constexpr int HPW = 64 / C;        // heads fully covered by one wave
    __shared__ __align__(16) short As[128 * 64];
    __shared__ __align__(16) short Bs[128 * 64];
    int bx = blockIdx.x % colTiles;
    int by = blockIdx.x / colTiles;
    int row0 = by * 128, col0 = bx * 128;
    int t = threadIdx.x;
    int lane = t & 63, w = t >> 6;
    int wr = (w >> 1) * 64, wc = (w & 1) * 64;
    int lrow = lane & 15, lq = lane >> 4;

    int srow = lane >> 3;              // 0..7 row within 8-row group
    int kcsrc = (lane & 7) ^ srow;     // swizzled source k-chunk

    floatx4 acc[4][4];
#pragma unroll
    for (int i = 0; i < 4; i++)
#pragma unroll
        for (int j = 0; j < 4; j++) acc[i][j] = (floatx4)0.0f;

    for (int k0 = 0; k0 < K; k0 += 64) {
#pragma unroll
        for (int it = 0; it < 4; it++) {
            int r0 = w * 32 + it * 8;
            int r = r0 + srow;
            gl_lds16(&A[(size_t)(row0 + r) * K + k0 + kcsrc * 8], &As[r0 * 64]);
            gl_lds16(&B[(size_t)(col0 + r) * K + k0 + kcsrc * 8], &Bs[r0 * 64]);
        }
        __syncthreads();
#pragma unroll
        for (int kk = 0; kk < 2; kk++) {
            int slot = (kk * 4 + lq) ^ (lrow & 7);
            short8 af[4], bfr[4];
#pragma unroll
            for (int i = 0; i < 4; i++)
                af[i] = *(const short8*)&As[(wr + i * 16 + lrow) * 64 + slot * 8];
#pragma unroll
            for (int j = 0; j < 4; j++)
                bfr[j] = *(const short8*)&Bs[(wc + j * 16 + lrow) * 64 + slot * 8];
#pragma unroll
            for (int i = 0; i < 4; i++)
#pragma unroll
                for (int j = 0; j < 4; j++)
                    acc[i][j] = __builtin_amdgcn_mfma_f32_16x16x32_bf16(af[i], bfr[j], acc[i][j], 0, 0, 0);
        }
        __syncthreads();
    }

    // ---- C store (D layout: row=wr+i*16+lq*4+r, col=wc+j*16+lrow)
#pragma unroll
    for (int i = 0; i < 4; i++)
#pragma unroll
        for (int j = 0; j < 4; j++)
#pragma unroll
            for (int r = 0; r < 4; r++) {
                int row = row0 + wr + i * 16 + lq * 4 + r;
                int col = col0 + wc + j * 16 + lrow;
                Cout[(size_t)row * Nc + col] = f2bf(acc[i][j][r]);
            }

    // ---- fused es/ed epilogue (a_s flat [H*C] == abs col index)
    float asv[4], adv[4];
#pragma unroll
    for (int j = 0; j < 4; j++) {
        int colA = col0 + wc + j * 16 + lrow;
        asv[j] = a_s[colA];
        adv[j] = a_d[colA];
    }
    int hb = (col0 + wc) / C;
#pragma unroll
    for (int i = 0; i < 4; i++)
#pragma unroll
        for (int r = 0; r < 4; r++) {
            float s_h[HPW], d_h[HPW];
#pragma unroll
            for (int hh = 0; hh < HPW; hh++) { s_h[hh] = 0.f; d_h[hh] = 0.f; }
#pragma unroll
            for (int j = 0; j < 4; j++) {
                s_h[j / JPH] = fmaf(acc[i][j][r], asv[j], s_h[j / JPH]);
                d_h[j / JPH] = fmaf(acc[i][j][r], adv[j], d_h[j / JPH]);
            }
#pragma unroll
            for (int hh = 0; hh < HPW; hh++) {
#pragma unroll
                for (int off = 1; off <= 8; off <<= 1) {
                    s_h[hh] += __shfl_xor(s_h[hh], off);
                    d_h[hh] += __shfl_xor(d_h[hh], off);
                }
            }
            if (lrow == 0) {
                int row = row0 + wr + i * 16 + lq * 4 + r;
                if (row < NN) {
#pragma unroll
                    for (int hh = 0; hh < HPW; hh++) {
                        es[row * 8 + hb + hh] = s_h[hh];
                        ed[row * 8 + hb + hh] = d_h[hh];
                    }
                }
            }
        }
}

// ---------------------------------------------------------------------------
// alpha: one wave per node, online softmax over REAL deg (degr), register-
// stashed logits, HEAD-MAJOR alpha[h*NEPP+e]; zero-fills pad slots
// [deg, degp) so the padded aggr loop contributes exactly 0 there.
// ---------------------------------------------------------------------------
__global__ __launch_bounds__(256) void alpha_kernel(const float* __restrict__ es,
                                                    const float* __restrict__ ed,
                                                    const int* __restrict__ row_ptr,
                                                    const int* __restrict__ degr,
                                                    const int* __restrict__ srcs,
                                                    float* __restrict__ alpha) {
    int wave = threadIdx.x >> 6, lane = threadIdx.x & 63;
    int n = __builtin_amdgcn_readfirstlane(blockIdx.x * 4 + wave);
    int start = row_ptr[n];            // uniform -> s_load
    int degp = row_ptr[n + 1] - start; // padded (%4==0)
    int deg = degr[n];                 // real
    int m8 = deg * 8;
    int mp8 = degp * 8;
    const int* sp = srcs + start;      // uniform base
    int hh = lane & 7;                 // idx&7 == lane&7 for idx = lane+i*64
    float edv = ed[n * 8 + hh];
    float st[KSTASH];
    float pm = -1e30f, ps = 0.f;
#pragma unroll
    for (int i = 0; i < KSTASH; i++) {
        int idx = lane + i * 64;
        if (idx < m8) {
            int s = sp[idx >> 3];
            float e = es[s * 8 + hh] + edv;
            e = e > 0.f ? e : 0.2f * e;
            st[i] = e;
            float mn = fmaxf(pm, e);
            ps = ps * __expf(pm - mn) + __expf(e - mn);
            pm = mn;
        }
    }
    for (int idx = lane + KSTASH * 64; idx < m8; idx += 64) {   // rare
        int s = sp[idx >> 3];
        float e = es[s * 8 + hh] + edv;
        e = e > 0.f ? e : 0.2f * e;
        float mn = fmaxf(pm, e);
        ps = ps * __expf(pm - mn) + __expf(e - mn);
        pm = mn;
    }
    // per-head reduce: head lives on lane&7; combine lane bits 3,4,5
#pragma unroll
    for (int off = 8; off <= 32; off <<= 1) {
        float mo = __shfl_xor(pm, off);
        float so = __shfl_xor(ps, off);
        float mn = fmaxf(pm, mo);
        ps = ps * __expf(pm - mn) + so * __expf(mo - mn);
        pm = mn;
    }
    float invd = 1.0f / ps;
    int hoff = hh * NEPP;
    // head-major write: lane (k-group, head hh) -> alpha[hh*NEPP + start + k]
#pragma unroll
    for (int i = 0; i < KSTASH; i++) {
        int idx = lane + i * 64;
        if (idx < m8) alpha[hoff + start + (idx >> 3)] = __expf(st[i] - pm) * invd;
    }
    for (int idx = lane + KSTASH * 64; idx < m8; idx += 64) {   // rare
        int s = sp[idx >> 3];
        float e = es[s * 8 + hh] + edv;
        e = e > 0.f ? e : 0.2f * e;
        alpha[hoff + start + (idx >> 3)] = __expf(e - pm) * invd;
    }
    // pad slots -> 0 (<=24 values; head/edge derived from idx, not lane)
    for (int idx = m8 + lane; idx < mp8; idx += 64)
        alpha[(size_t)(idx & 7) * NEPP + start + (idx >> 3)] = 0.f;
}

// ---------------------------------------------------------------------------
// R16 aggregate: node-per-group feature-chunked gather, U=4, PADDED degrees.
// R15 counters: 109us @ C=64, VALUBusy 37%, HBM 37%, FETCH 265MB -> latency-
// bound (neither pipe saturated; U=2 = two dependent round-trips per 2 edges).
// R16: 4 edges in flight (round-trip pairs per node deg/4 ~ 4.3, was 8.5) and
// deg padded to %4 at CSR build -> no tail code, uniform loop. Pad slots:
// srcs=0 (row-0 gather, L2-hot) x alpha=0 -> exact zero contribution.
// Traffic structure unchanged: 128B row-chunks, chunk = blockIdx % NCH.
// ---------------------------------------------------------------------------
template <int C, bool ELU>
__global__ __launch_bounds__(256) void aggr_npg(const short* __restrict__ h,
                                                const float* __restrict__ alpha,
                                                const int* __restrict__ row_ptr,
                                                const int* __restrict__ srcs,
                                                const float* __restrict__ bias,
                                                short* __restrict__ out) {
    constexpr int HC = NHEAD * C;
    constexpr int NCH = HC / 64;       // 8 / 4 / 2 chunks
    constexpr int RSH = (C == 64) ? 10 : (C == 32) ? 9 : 8;   // log2(HC*2)
    int chunk = blockIdx.x % NCH;
    int grp   = blockIdx.x / NCH;      // 32-node block
    int lane = threadIdx.x & 63;
    int wave = threadIdx.x >> 6;
    int sub = lane & 7;                // channel octet within chunk
    int g   = lane >> 3;               // node group within wave 0..7
    int n = grp * 32 + wave * 8 + g;   // this group's node
    int c0 = chunk * 64 + sub * 8;     // absolute channel of this lane's 16B
    unsigned c02 = (unsigned)(c0 * 2); // byte offset within row
    int head = c0 / C;
    bool valid = n < NN;
    int start = 0, degp = 0;
    if (valid) {
        start = row_ptr[n];
        degp = row_ptr[n + 1] - start; // padded, %4==0
    }
    unsigned soff = (unsigned)start;                  // srcs elem offset
    unsigned aoff = (unsigned)(head * NEPP + start);  // alpha elem offset
    float acc[8];
#pragma unroll
    for (int j = 0; j < 8; j++) acc[j] = 0.f;
    for (int k = 0; k < degp; k += 4) {   // uniform U=4, no tail
        int s0 = srcs[soff + k];
        int s1 = srcs[soff + k + 1];
        int s2 = srcs[soff + k + 2];
        int s3 = srcs[soff + k + 3];
        float w0 = alpha[aoff + k];
        float w1 = alpha[aoff + k + 1];
        float w2 = alpha[aoff + k + 2];
        float w3 = alpha[aoff + k + 3];
        uintx4 h0 = *(const uintx4*)((const char*)h + (((unsigned)s0 << RSH) + c02));
        uintx4 h1 = *(const uintx4*)((const char*)h + (((unsigned)s1 << RSH) + c02));
        uintx4 h2 = *(const uintx4*)((const char*)h + (((unsigned)s2 << RSH) + c02));
        uintx4 h3 = *(const uintx4*)((const char*)h + (((unsigned)s3 << RSH) + c02));
#pragma unroll
        for (int j = 0; j < 4; j++) {
            acc[2 * j]     = fmaf(w0, bf2f_lo(h0[j]), acc[2 * j]);
            acc[2 * j + 1] = fmaf(w0, bf2f_hi(h0[j]), acc[2 * j + 1]);
        }
#pragma unroll
        for (int j = 0; j < 4; j++) {
            acc[2 * j]     = fmaf(w1, bf2f_lo(h1[j]), acc[2 * j]);
            acc[2 * j + 1] = fmaf(w1, bf2f_hi(h1[j]), acc[2 * j + 1]);
        }
#pragma unroll
        for (int j = 0; j < 4; j++) {
            acc[2 * j]     = fmaf(w2, bf2f_lo(h2[j]), acc[2 * j]);
            acc[2 * j + 1] = fmaf(w2, bf2f_hi(h2[j]), acc[2 * j + 1]);
        }
#pragma unroll
        for (int j = 0; j < 4; j++) {
            acc[2 * j]     = fmaf(w3, bf2f_lo(h3[j]), acc[2 * j]);
            acc[2 * j + 1] = fmaf(w3, bf2f_hi(h3[j]), acc[2 * j + 1]);
        }
    }
    if (valid) {
        floatx4 b0 = *(const floatx4*)&bias[c0];
        floatx4 b1 = *(const floatx4*)&bias[c0 + 4];
        float bb[8] = {b0[0], b0[1], b0[2], b0[3], b1[0], b1[1], b1[2], b1[3]};
        unsigned pk[4];
#pragma unroll
        for (int j = 0; j < 4; j++) {
            float o0 = acc[2 * j] + bb[2 * j];
            float o1 = acc[2 * j + 1] + bb[2 * j + 1];
            if (ELU) {
                o0 = o0 > 0.f ? o0 : (__expf(o0) - 1.0f);
                o1 = o1 > 0.f ? o1 : (__expf(o1) - 1.0f);
            }
            pk[j] = ((unsigned)(unsigned short)f2bf(o0)) |
                    (((unsigned)(unsigned short)f2bf(o1)) << 16);
        }
        *(uintx4*)&out[(size_t)n * HC + c0] = *(uintx4*)pk;
    }
}

// ---------------------------------------------------------------------------
// Global mean pool: 64 graphs x 8 chunks of 64 ch; 16B/lane loads,
// shfl stripe-reduce within wave, tiny LDS combine across 4 waves.
// ---------------------------------------------------------------------------
__global__ __launch_bounds__(256) void pool_kernel(const short* __restrict__ h,
                                                   const int* __restrict__ batch,
                                                   float* __restrict__ gout) {
    __shared__ float red[4 * 64];
    int g = blockIdx.x >> 3;
    int fc = (blockIdx.x & 7) * 64;
    int lo = 0, hi = NN;
    while (lo < hi) { int mid = (lo + hi) >> 1; if (batch[mid] < g) lo = mid + 1; else hi = mid; }
    int s = lo;
    lo = 0; hi = NN;
    while (lo < hi) { int mid = (lo + hi) >> 1; if (batch[mid] < g + 1) lo = mid + 1; else hi = mid; }
    int e = lo;
    int t = threadIdx.x;
    int wave = t >> 6, lane = t & 63;
    int f8 = (lane & 7) * 8;           // 8 channels per lane within the 64-chunk
    int stripe = wave * 8 + (lane >> 3);   // 0..31 row stripes
    float acc[8];
#pragma unroll
    for (int j = 0; j < 8; j++) acc[j] = 0.f;
    for (int r = s + stripe; r < e; r += 32) {
        short8 v = *(const short8*)&h[(size_t)r * 512 + fc + f8];
#pragma unroll
        for (int j = 0; j < 8; j++) acc[j] += bf2f(v[j]);
    }
    // reduce 8 stripes within the wave (lane bits 3,4,5)
#pragma unroll
    for (int j = 0; j < 8; j++) {
        acc[j] += __shfl_xor(acc[j], 8);
        acc[j] += __shfl_xor(acc[j], 16);
        acc[j] += __shfl_xor(acc[j], 32);
    }
    if (lane < 8) {
#pragma unroll
        for (int j = 0; j < 8; j++) red[wave * 64 + lane * 8 + j] = acc[j];
    }
    __syncthreads();
    if (t < 64) {                      // t = ch within chunk
        float v = red[t] + red[64 + t] + red[128 + t] + red[192 + t];
        float inv = 1.0f / fmaxf((float)(e - s), 1.0f);
        gout[g * 512 + fc + t] = v * inv;
    }
}

// ---------------------------------------------------------------------------
// Final MLP: [64,512] -> elu(@lw1^T+lb1) -> @lw2^T+lb2 -> [64,2]
// ---------------------------------------------------------------------------
__global__ __launch_bounds__(64) void mlp_kernel(const float* __restrict__ g,
                                                 const float* __restrict__ lw1,
                                                 const float* __restrict__ lb1,
                                                 const float* __restrict__ lw2,
                                                 const float* __restrict__ lb2,
                                                 float* __restrict__ outp) {
    __shared__ float gv[512];
    __shared__ float y1[32];
    int b = blockIdx.x, t = threadIdx.x;
    for (int i = t; i < 512; i += 64) gv[i] = g[b * 512 + i];
    __syncthreads();
    if (t < 32) {
        float a = lb1[t];
        for (int k = 0; k < 512; k++) a = fmaf(gv[k], lw1[t * 512 + k], a);
        y1[t] = a > 0.f ? a : (__expf(a) - 1.0f);
    }
    __syncthreads();
    if (t < 2) {
        float a = lb2[t];
        for (int k = 0; k < 32; k++) a = fmaf(y1[k], lw2[t * 32 + k], a);
        outp[b * 2 + t] = a;
    }
}

// ---------------------------------------------------------------------------
// Launch
// ---------------------------------------------------------------------------
extern "C" void kernel_launch(void* const* d_in, const int* in_sizes, int n_in,
                              void* d_out, int out_size, void* d_ws, size_t ws_size,
                              hipStream_t stream) {
    (void)in_sizes; (void)n_in; (void)out_size; (void)ws_size;
    const float* x     = (const float*)d_in[0];
    const int*   ei    = (const int*)d_in[1];
    const int*   batch = (const int*)d_in[2];
    const float* W[4]  = {(const float*)d_in[3], (const float*)d_in[7],
                          (const float*)d_in[11], (const float*)d_in[15]};
    const float* As_[4] = {(const float*)d_in[4], (const float*)d_in[8],
                           (const float*)d_in[12], (const float*)d_in[16]};
    const float* Ad_[4] = {(const float*)d_in[5], (const float*)d_in[9],
                           (const float*)d_in[13], (const float*)d_in[17]};
    const float* Bi[4]  = {(const float*)d_in[6], (const float*)d_in[10],
                           (const float*)d_in[14], (const float*)d_in[18]};
    const float* lw1 = (const float*)d_in[19];
    const float* lb1 = (const float*)d_in[20];
    const float* lw2 = (const float*)d_in[21];
    const float* lb2 = (const float*)d_in[22];
    float* out = (float*)d_out;

    // workspace layout (bf16 buffers as short)
    short* Ab = (short*)d_ws;                      // [MPAD*512] activations
    short* Hb = Ab + (size_t)MPAD * 512;           // [MPAD*512] h = act @ W^T
    short* Wb = Hb + (size_t)MPAD * 512;           // bf16 weights (contiguous)
    short* Wb_[4] = {Wb, Wb + 65536, Wb + 196608, Wb + 229376};
    float* esb  = (float*)(Wb + 294912);           // [NN*8]
    float* edb  = esb + NN * NHEAD;                // [NN*8]
    float* gbuf = edb + NN * NHEAD;                // [64*512]
    int* row_ptr = (int*)(gbuf + NGR * 512);       // [NN+1] padded CSR
    int* cursor  = row_ptr + (NN + 1);             // [NN+1]
    int* degr    = cursor + (NN + 1);              // [NN] real degrees
    int* srcs    = degr + NN;                      // [NEPP]
    int* bsum    = srcs + NEPP;                    // [64]
    float* alphab = (float*)(bsum + 64);           // [8*NEPP] head-major alpha

    const int nblk = (NN + 1023) / 1024;           // 49

    // ---- CSR build (padded degrees; shared by all 4 layers)
    hipMemsetAsync(degr, 0, NN * sizeof(int), stream);
    count_deg<<<(NEP + 255) / 256, 256, 0, stream>>>(ei, degr);
    scan_local<<<nblk, 1024, 0, stream>>>(degr, row_ptr, bsum, NN);
    scan_bsum<<<1, 64, 0, stream>>>(bsum, nblk);
    scan_add<<<(NN + 256) / 256, 256, 0, stream>>>(row_ptr, cursor, bsum, NN, nblk);
    hipMemsetAsync(srcs, 0, NEPP * sizeof(int), stream);
    scatter_edges<<<(NEP + 255) / 256, 256, 0, stream>>>(ei, cursor, srcs);

    // ---- bf16 conversions
    conv_x_pad4<<<(MPAD * 32 + 255) / 256, 256, 0, stream>>>(x, Ab);
    conv_w_all<<<(294912 + 255) / 256, 256, 0, stream>>>(W[0], W[1], W[2], W[3], Wb);

    const int rowTiles = MPAD / 128;               // 391
    const int ag  = NN / 4;                        // alpha grid: 1 wave/node
    const int ngb = (NN + 31) / 32;                // aggr: 32 nodes per block

    // ---- layer 1: 128 -> 512 (C=64), ELU
    gemm_bf<64><<<rowTiles * 4, 256, 0, stream>>>(Ab, Wb_[0], Hb, As_[0], Ad_[0], esb, edb, 128);
    alpha_kernel<<<ag, 256, 0, stream>>>(esb, edb, row_ptr, degr, srcs, alphab);
    aggr_npg<64, true><<<ngb * 8, 256, 0, stream>>>(Hb, alphab, row_ptr, srcs, Bi[0], Ab);

    // ---- layer 2: 512 -> 256 (C=32), ELU
    gemm_bf<32><<<rowTiles * 2, 256, 0, stream>>>(Ab, Wb_[1], Hb, As_[1], Ad_[1], esb, edb, 512);
    alpha_kernel<<<ag, 256, 0, stream>>>(esb, edb, row_ptr, degr, srcs, alphab);
    aggr_npg<32, true><<<ngb * 4, 256, 0, stream>>>(Hb, alphab, row_ptr, srcs, Bi[1], Ab);

    // ---- layer 3: 256 -> 128 (C=16), ELU
    gemm_bf<16><<<rowTiles * 1, 256, 0, stream>>>(Ab, Wb_[2], Hb, As_[2], Ad_[2], esb, edb, 256);
    alpha_kernel<<<ag, 256, 0, stream>>>(esb, edb, row_ptr, degr, srcs, alphab);
    aggr_npg<16, true><<<ngb * 2, 256, 0, stream>>>(Hb, alphab, row_ptr, srcs, Bi[2], Ab);

    // ---- layer 4: 128 -> 512 (C=64), no ELU
    gemm_bf<64><<<rowTiles * 4, 256, 0, stream>>>(Ab, Wb_[3], Hb, As_[3], Ad_[3], esb, edb, 128);
    alpha_kernel<<<ag, 256, 0, stream>>>(esb, edb, row_ptr, degr, srcs, alphab);
    aggr_npg<64, false><<<ngb * 8, 256, 0, stream>>>(Hb, alphab, row_ptr, srcs, Bi[3], Ab);

    // ---- pool + MLP
    pool_kernel<<<NGR * 8, 256, 0, stream>>>(Ab, batch, gbuf);
    mlp_kernel<<<NGR, 64, 0, stream>>>(gbuf, lw1, lb1, lw2, lb2, out);
}